// Round 15
// baseline (168.235 us; speedup 1.0000x reference)
//
#include <hip/hip_runtime.h>
#include <hip/hip_bf16.h>

// Fused causal MHA block for MI355X (gfx950).
// B=4 S=2048 H=1024 NH=16 DK=64. Inputs f32; compute in bf16 MFMA (f32 accum).
// Pipeline: cvt(x) | transpose-cvt(W) | GEMM qkv (R10 form: 2-barrier ring-3,
// scatter FUSEV) | flash v4 (2-buffer, restored per R13 decision rule, with
// launch_bounds(256,5): LDS allows 5 blocks/CU, VGPR 84 <= 102 cap) | proj.
// R13 falsified flash ring-3 (occupancy loss > prefetch gain). R10 = best total.

typedef __attribute__((ext_vector_type(8))) short bhalf8;    // 8 bf16 = 4 VGPRs
typedef __attribute__((ext_vector_type(4))) float floatx4;   // MFMA 16x16 accum
typedef __attribute__((ext_vector_type(16))) float floatx16; // MFMA 32x32 accum

#define SB 2048
#define HB 1024
#define H3 3072

#if __has_builtin(__builtin_amdgcn_exp2f)
#define EXP2(x) __builtin_amdgcn_exp2f(x)
#else
#define EXP2(x) exp2f(x)
#endif

__device__ __forceinline__ float bf2f(unsigned short u) {
  union { unsigned int i; float f; } c; c.i = ((unsigned int)u) << 16; return c.f;
}
__device__ __forceinline__ unsigned short f2bf(float f) {
  union { float f; unsigned int i; } c; c.f = f;
  unsigned int r = c.i + 0x7fffu + ((c.i >> 16) & 1u);   // RNE
  return (unsigned short)(r >> 16);
}
__device__ __forceinline__ int pkbf(float lo, float hi_) {
  union { __hip_bfloat162 h; int i; } u;
  u.h = __float22bfloat162_rn(make_float2(lo, hi_));  // lo -> bits 0..15
  return u.i;
}

// async global->LDS, 16B per lane (dest must be uniform-base + lane*16).
__device__ __forceinline__ void gl_lds16(const unsigned short* g, unsigned short* l) {
  __builtin_amdgcn_global_load_lds(
      (const __attribute__((address_space(1))) unsigned int*)g,
      (__attribute__((address_space(3))) unsigned int*)l, 16, 0, 0);
}

#define REP16(OP) OP(0) OP(1) OP(2) OP(3) OP(4) OP(5) OP(6) OP(7) \
                  OP(8) OP(9) OP(10) OP(11) OP(12) OP(13) OP(14) OP(15)

// ---------------- elementwise f32 -> bf16 ----------------
__global__ void cvt_f32_bf16(const float* __restrict__ in, unsigned short* __restrict__ out, int n) {
  int i = (blockIdx.x * blockDim.x + threadIdx.x) * 4;
  if (i >= n) return;
  float4 v = *(const float4*)(in + i);
  ushort4 o;
  o.x = f2bf(v.x); o.y = f2bf(v.y); o.z = f2bf(v.z); o.w = f2bf(v.w);
  *(ushort4*)(out + i) = o;
}

// ---------------- W[K][N] f32 -> Wt[N][K] bf16 (tiled transpose) ----------------
__global__ void transpose_cvt(const float* __restrict__ in, unsigned short* __restrict__ out,
                              int K, int N) {
  __shared__ float tile[32][33];
  int n0 = blockIdx.x * 32, k0 = blockIdx.y * 32;
  for (int i = threadIdx.y; i < 32; i += 8)
    tile[i][threadIdx.x] = in[(size_t)(k0 + i) * N + n0 + threadIdx.x];
  __syncthreads();
  for (int i = threadIdx.y; i < 32; i += 8)
    out[(size_t)(n0 + i) * K + k0 + threadIdx.x] = f2bf(tile[threadIdx.x][i]);
}

// ---------------- V part of qkv -> Vt[bh*64+dk][S] (fallback path only) ----------------
__global__ void transpose_v(const unsigned short* __restrict__ qkv,
                            unsigned short* __restrict__ Vt) {
  __shared__ unsigned short tile[32][33];
  const int bh = blockIdx.z;
  const int b = bh >> 4, h = bh & 15;
  const int s0 = blockIdx.x * 32;
  const int d0 = blockIdx.y * 32;
  const int tx = threadIdx.x;
  const unsigned short* src = qkv + (size_t)(b * SB + s0) * H3 + 2 * HB + h * 64 + d0;
  for (int i = threadIdx.y; i < 32; i += 8)
    tile[i][tx] = src[(size_t)i * H3 + tx];
  __syncthreads();
  unsigned short* dst = Vt + ((size_t)bh * 64 + d0) * SB + s0;
  for (int i = threadIdx.y; i < 32; i += 8)
    dst[(size_t)i * SB + tx] = tile[tx][i];
}

// ---------------- GEMM (qkv, R10 form): C[M=8192][N=3072] = A @ Bt^T + bias ----
// BM=256 BN=384 BK=32. 512 thr = 8 waves (2Mx4N), wave tile 128x96 (acc 8x6).
// Ring-3 slots of 40KB; 5 gl_lds16/thread/tile staged 2 ahead; vmcnt(5) at tile
// top; 2 barriers/tile. FUSEV: V cols (>=2048) scatter-stored to Vt.
template <bool FUSEV>
__global__ __launch_bounds__(512, 2) void gemm_v9(
    const unsigned short* __restrict__ A,
    const unsigned short* __restrict__ Bt,
    const float* __restrict__ bias,
    unsigned short* __restrict__ C,
    unsigned short* __restrict__ Vt,
    int M, int N, int K) {
  __shared__ __align__(16) unsigned short Sm[3 * 20480];   // 122880 B
  const int tid = threadIdx.x;
  const int lane = tid & 63;
  const int w = tid >> 6;
  const int l15 = lane & 15, l4 = lane >> 4;
  const int wm = w >> 2, wn = w & 3;

  // bijective XCD swizzle (grid = 256, %8==0)
  const int gx = gridDim.x;               // 8
  int lin = blockIdx.y * gx + blockIdx.x;
  const int cpx = (gx * gridDim.y) >> 3;
  lin = (lin & 7) * cpx + (lin >> 3);
  const int m0 = (lin / gx) * 256;
  const int n0 = (lin % gx) * 384;

  const int rb0 = tid >> 2;
  const int co = (((tid & 3) ^ ((tid >> 3) & 3)) * 8);
  const unsigned short* pA0 = A + (size_t)(m0 + rb0) * K + co;
  const unsigned short* pA1 = pA0 + (size_t)128 * K;
  const unsigned short* pB0 = Bt + (size_t)(n0 + rb0) * K + co;
  const unsigned short* pB1 = pB0 + (size_t)128 * K;
  const unsigned short* pB2 = pB0 + (size_t)256 * K;

  const int ra0 = wm * 128 + l15;
  const int ab0 = ra0 * 64 + ((l4 ^ ((ra0 >> 1) & 3)) << 4);
  const int rbq = wn * 96 + l15;
  const int bb0 = 16384 + rbq * 64 + ((l4 ^ ((rbq >> 1) & 3)) << 4);

  const floatx4 zero = {0.f, 0.f, 0.f, 0.f};
  floatx4 acc[8][6];
#pragma unroll
  for (int i = 0; i < 8; ++i)
#pragma unroll
    for (int j = 0; j < 6; ++j) acc[i][j] = zero;

#define STAGE_A(k0, ss)                                                 \
  { gl_lds16(pA0 + (k0), Sm + (ss) + tid * 8);                          \
    gl_lds16(pA1 + (k0), Sm + (ss) + (tid + 512) * 8); }
#define STAGE_B(k0, ss)                                                 \
  { gl_lds16(pB0 + (k0), Sm + (ss) + 8192 + tid * 8);                   \
    gl_lds16(pB1 + (k0), Sm + (ss) + 8192 + (tid + 512) * 8);           \
    gl_lds16(pB2 + (k0), Sm + (ss) + 8192 + (tid + 1024) * 8); }

  const int NT = K >> 5;                  // 32
  STAGE_A(0, 0)      STAGE_B(0, 0)
  STAGE_A(32, 20480) STAGE_B(32, 20480)
  int sb = 0;
  int ss = 40960;

  for (int t = 0; t < NT; ++t) {
    if (t < NT - 1) asm volatile("s_waitcnt vmcnt(5)" ::: "memory");
    else            asm volatile("s_waitcnt vmcnt(0)" ::: "memory");
    __builtin_amdgcn_s_barrier();   // top barrier: tile t resident; orders slot reuse.

    const char* LB = (const char*)(Sm + sb);
    const int k2 = (t + 2) * 32;
    const bool st = (t + 2 < NT);

    // ---- phase 1: A0..A3 x B0..B5 ----
    bhalf8 a0 = *(const bhalf8*)(LB + ab0);
    bhalf8 a1 = *(const bhalf8*)(LB + ab0 + 1024);
    bhalf8 a2 = *(const bhalf8*)(LB + ab0 + 2048);
    bhalf8 a3 = *(const bhalf8*)(LB + ab0 + 3072);
    bhalf8 b0 = *(const bhalf8*)(LB + bb0);
    bhalf8 b1 = *(const bhalf8*)(LB + bb0 + 1024);
    bhalf8 b2 = *(const bhalf8*)(LB + bb0 + 2048);
    bhalf8 b3 = *(const bhalf8*)(LB + bb0 + 3072);
    bhalf8 b4 = *(const bhalf8*)(LB + bb0 + 4096);
    bhalf8 b5 = *(const bhalf8*)(LB + bb0 + 5120);
    if (st) STAGE_A(k2, ss)
    __builtin_amdgcn_s_setprio(1);
#define MROW(i, av)                                                              \
    acc[i][0] = __builtin_amdgcn_mfma_f32_16x16x32_bf16(av, b0, acc[i][0], 0, 0, 0); \
    acc[i][1] = __builtin_amdgcn_mfma_f32_16x16x32_bf16(av, b1, acc[i][1], 0, 0, 0); \
    acc[i][2] = __builtin_amdgcn_mfma_f32_16x16x32_bf16(av, b2, acc[i][2], 0, 0, 0); \
    acc[i][3] = __builtin_amdgcn_mfma_f32_16x16x32_bf16(av, b3, acc[i][3], 0, 0, 0); \
    acc[i][4] = __builtin_amdgcn_mfma_f32_16x16x32_bf16(av, b4, acc[i][4], 0, 0, 0); \
    acc[i][5] = __builtin_amdgcn_mfma_f32_16x16x32_bf16(av, b5, acc[i][5], 0, 0, 0);
    MROW(0, a0) MROW(1, a1) MROW(2, a2) MROW(3, a3)
    __builtin_amdgcn_s_setprio(0);
    __builtin_amdgcn_s_barrier();          // mid-tile lockstep

    // ---- phase 2: A4..A7 x B0..B5 ----
    bhalf8 a4 = *(const bhalf8*)(LB + ab0 + 4096);
    bhalf8 a5 = *(const bhalf8*)(LB + ab0 + 5120);
    bhalf8 a6 = *(const bhalf8*)(LB + ab0 + 6144);
    bhalf8 a7 = *(const bhalf8*)(LB + ab0 + 7168);
    if (st) STAGE_B(k2, ss)
    __builtin_amdgcn_s_setprio(1);
    MROW(4, a4) MROW(5, a5) MROW(6, a6) MROW(7, a7)
#undef MROW
    __builtin_amdgcn_s_setprio(0);
    // no end barrier: next iteration's top barrier orders slot reuse (ring-3).

    sb = (sb == 40960) ? 0 : sb + 20480;
    ss = (ss == 40960) ? 0 : ss + 20480;
  }
#undef STAGE_A
#undef STAGE_B

#pragma unroll
  for (int i = 0; i < 8; ++i) {
    int row = m0 + wm * 128 + i * 16 + (l4 << 2);
#pragma unroll
    for (int j = 0; j < 6; ++j) {
      int col = n0 + wn * 96 + j * 16 + l15;
      float bb = bias[col];
      if (!FUSEV || col < 2048) {
#pragma unroll
        for (int r = 0; r < 4; ++r)
          C[(size_t)(row + r) * N + col] = f2bf(acc[i][j][r] + bb);
      } else {
        // V section: scatter to per-head transposed Vt[(b*16+h)*64+dk][s]
        int vc = col - 2048;
        int h2 = vc >> 6, dk = vc & 63;
        int b2 = row >> 11, s = row & 2047;
        ushort4 pv;
        pv.x = f2bf(acc[i][j][0] + bb);
        pv.y = f2bf(acc[i][j][1] + bb);
        pv.z = f2bf(acc[i][j][2] + bb);
        pv.w = f2bf(acc[i][j][3] + bb);
        *(ushort4*)(Vt + ((size_t)((b2 * 16 + h2) * 64 + dk)) * SB + s) = pv;
      }
    }
  }
}

// ---------------- GEMM v6 (proj, R10 form): C = A @ Bt^T + bias ----------------
// BM=256 BN=128 BK=32. 512 thr = 8 waves (4Mx2N, 64x64). Ring-3, 2 barriers/tile.
template <bool F32OUT>
__global__ __launch_bounds__(512, 4) void gemm_v6(
    const unsigned short* __restrict__ A,
    const unsigned short* __restrict__ Bt,
    const float* __restrict__ bias,
    void* __restrict__ Cv,
    int M, int N, int K) {
  __shared__ __align__(16) unsigned short Sm[3 * 12288];   // 73728 B
  const int tid = threadIdx.x;
  const int lane = tid & 63;
  const int w = tid >> 6;
  const int l15 = lane & 15, l4 = lane >> 4;
  const int wr = (w >> 1) * 64;
  const int wc = (w & 1) * 64;

  const int gx = gridDim.x;
  int lin = blockIdx.y * gx + blockIdx.x;
  const int cpx = (gx * gridDim.y) >> 3;
  lin = (lin & 7) * cpx + (lin >> 3);
  const int m0 = (lin / gx) * 256;
  const int n0 = (lin % gx) * 128;

  const int idx0 = tid, idx1 = tid + 512;
  const unsigned short* pA0 = A + (size_t)(m0 + (idx0 >> 2)) * K + (((idx0 & 3) ^ ((idx0 >> 3) & 3)) * 8);
  const unsigned short* pA1 = A + (size_t)(m0 + (idx1 >> 2)) * K + (((idx1 & 3) ^ ((idx1 >> 3) & 3)) * 8);
  const unsigned short* pB  = Bt + (size_t)(n0 + (tid >> 2)) * K + (((tid & 3) ^ ((tid >> 3) & 3)) * 8);

  int abyte[4], bbyte[4];
#pragma unroll
  for (int i = 0; i < 4; ++i) {
    int ra = wr + i * 16 + l15;
    abyte[i] = ra * 64 + ((l4 ^ ((ra >> 1) & 3)) << 4);
    int rb = wc + i * 16 + l15;
    bbyte[i] = 16384 + rb * 64 + ((l4 ^ ((rb >> 1) & 3)) << 4);
  }

  const floatx4 zero = {0.f, 0.f, 0.f, 0.f};
  floatx4 acc[4][4];
#pragma unroll
  for (int i = 0; i < 4; ++i)
#pragma unroll
    for (int j = 0; j < 4; ++j) acc[i][j] = zero;

#define STAGE_A6(k0, sbase)                                             \
  { gl_lds16(pA0 + (k0), Sm + (sbase) + idx0 * 8);                      \
    gl_lds16(pA1 + (k0), Sm + (sbase) + idx1 * 8); }
#define STAGE_B6(k0, sbase)                                             \
  { gl_lds16(pB + (k0), Sm + (sbase) + 8192 + tid * 8); }

  const int NT = K >> 5;
  STAGE_A6(0, 0)  STAGE_B6(0, 0)
  STAGE_A6(32, 12288) STAGE_B6(32, 12288)
  int sb = 0;
  int ss = 24576;

  for (int t = 0; t < NT; ++t) {
    if (t < NT - 1) asm volatile("s_waitcnt vmcnt(3)" ::: "memory");
    else            asm volatile("s_waitcnt vmcnt(0)" ::: "memory");
    __builtin_amdgcn_s_barrier();

    const char* LB = (const char*)(Sm + sb);
    const int k2 = (t + 2) * 32;
    const bool st = (t + 2 < NT);

    bhalf8 a0 = *(const bhalf8*)(LB + abyte[0]);
    bhalf8 a1 = *(const bhalf8*)(LB + abyte[1]);
    bhalf8 b0 = *(const bhalf8*)(LB + bbyte[0]);
    bhalf8 b1 = *(const bhalf8*)(LB + bbyte[1]);
    bhalf8 b2 = *(const bhalf8*)(LB + bbyte[2]);
    bhalf8 b3 = *(const bhalf8*)(LB + bbyte[3]);
    if (st) STAGE_A6(k2, ss)
    __builtin_amdgcn_s_setprio(1);
    acc[0][0] = __builtin_amdgcn_mfma_f32_16x16x32_bf16(a0, b0, acc[0][0], 0, 0, 0);
    acc[0][1] = __builtin_amdgcn_mfma_f32_16x16x32_bf16(a0, b1, acc[0][1], 0, 0, 0);
    acc[0][2] = __builtin_amdgcn_mfma_f32_16x16x32_bf16(a0, b2, acc[0][2], 0, 0, 0);
    acc[0][3] = __builtin_amdgcn_mfma_f32_16x16x32_bf16(a0, b3, acc[0][3], 0, 0, 0);
    acc[1][0] = __builtin_amdgcn_mfma_f32_16x16x32_bf16(a1, b0, acc[1][0], 0, 0, 0);
    acc[1][1] = __builtin_amdgcn_mfma_f32_16x16x32_bf16(a1, b1, acc[1][1], 0, 0, 0);
    acc[1][2] = __builtin_amdgcn_mfma_f32_16x16x32_bf16(a1, b2, acc[1][2], 0, 0, 0);
    acc[1][3] = __builtin_amdgcn_mfma_f32_16x16x32_bf16(a1, b3, acc[1][3], 0, 0, 0);
    __builtin_amdgcn_s_setprio(0);
    __builtin_amdgcn_s_barrier();          // mid-tile lockstep

    bhalf8 a2 = *(const bhalf8*)(LB + abyte[2]);
    bhalf8 a3 = *(const bhalf8*)(LB + abyte[3]);
    if (st) STAGE_B6(k2, ss)
    __builtin_amdgcn_s_setprio(1);
    acc[2][0] = __builtin_amdgcn_mfma_f32_16x16x32_bf16(a2, b0, acc[2][0], 0, 0, 0);
    acc[2][1] = __builtin_amdgcn_mfma_f32_16x16x32_bf16(a2, b1, acc[2][1], 0, 0, 0);
    acc[2][2] = __builtin_amdgcn_mfma_f32_16x16x32_bf16(a2, b2, acc[2][2], 0, 0, 0);
    acc[2][3] = __builtin_amdgcn_mfma_f32_16x16x32_bf16(a2, b3, acc[2][3], 0, 0, 0);
    acc[3][0] = __builtin_amdgcn_mfma_f32_16x16x32_bf16(a3, b0, acc[3][0], 0, 0, 0);
    acc[3][1] = __builtin_amdgcn_mfma_f32_16x16x32_bf16(a3, b1, acc[3][1], 0, 0, 0);
    acc[3][2] = __builtin_amdgcn_mfma_f32_16x16x32_bf16(a3, b2, acc[3][2], 0, 0, 0);
    acc[3][3] = __builtin_amdgcn_mfma_f32_16x16x32_bf16(a3, b3, acc[3][3], 0, 0, 0);
    __builtin_amdgcn_s_setprio(0);
    // no end barrier (ring-3 ordering via next top barrier)

    sb = (sb == 24576) ? 0 : sb + 12288;
    ss = (ss == 24576) ? 0 : ss + 12288;
  }
#undef STAGE_A6
#undef STAGE_B6

  float* Cf = (float*)Cv;
  unsigned short* Cb = (unsigned short*)Cv;
#pragma unroll
  for (int i = 0; i < 4; ++i) {
    int row = m0 + wr + i * 16 + (l4 << 2);
#pragma unroll
    for (int j = 0; j < 4; ++j) {
      int col = n0 + wc + j * 16 + l15;
      float bb = bias[col];
#pragma unroll
      for (int r = 0; r < 4; ++r) {
        float v = acc[i][j][r] + bb;
        size_t idx = (size_t)(row + r) * N + col;
        if constexpr (F32OUT) Cf[idx] = v;
        else Cb[idx] = f2bf(v);
      }
    }
  }
}

// ---------------- flash attention v4 (restored; occupancy 5 blocks/CU) ----------------
__global__ __launch_bounds__(256, 5) void flash_attn4(
    const unsigned short* __restrict__ qkv,   // [B*S][3H] bf16
    const unsigned short* __restrict__ Vt,    // [bh*64+dk][S] bf16
    unsigned short* __restrict__ outp) {      // [B*S][H]  bf16
  __shared__ __align__(16) unsigned short Sm[4 * 4096];

  const int tid = threadIdx.x;
  const int lane = tid & 63;
  const int w = tid >> 6;
  const int hi = lane >> 5;
  const int qc = lane & 31;
  const int bh = blockIdx.x;
  const int b = bh >> 4, h = bh & 15;
  const int qt = 15 - (int)blockIdx.y;   // big tiles dispatch first
  const int wq0 = qt * 128 + w * 32;
  const size_t rowbase = (size_t)b * SB;
  const int qg = wq0 + qc;
  const int nt = 2 * qt + 2;             // always even

  bhalf8 qf[4];
  {
    const unsigned short* qp = qkv + (rowbase + qg) * H3 + h * 64 + hi * 8;
#pragma unroll
    for (int kk = 0; kk < 4; ++kk) {
      bhalf8 v = *(const bhalf8*)(qp + kk * 16);
      bhalf8 o;
#pragma unroll
      for (int j = 0; j < 8; ++j)
        o[j] = (short)f2bf(bf2f((unsigned short)v[j]) * 0.18033688f);
      qf[kk] = o;
    }
  }

  const floatx16 Z16 = {0,0,0,0,0,0,0,0,0,0,0,0,0,0,0,0};
  floatx16 acc0 = Z16, acc1 = Z16;   // O^T: col q=qc, rows dk
  float l_half = 0.f;

  const char* LB = (const char*)Sm;
  int koff[8];
#pragma unroll
  for (int kk = 0; kk < 4; ++kk) {
    int xo = (((2 * kk + hi) ^ (qc & 7)) << 4);
    koff[2 * kk]     = qc * 128 + xo;
    koff[2 * kk + 1] = (32 + qc) * 128 + xo;
  }

  const int srow = tid >> 3, schk = tid & 7;
  const int sxe = (schk ^ (srow & 7)) * 8;
  const unsigned short* kp = qkv + (rowbase + srow) * H3 + HB + h * 64 + sxe;
  const unsigned short* vp = Vt + ((size_t)bh * 64 + srow) * SB + sxe;

  {
    unsigned short* kb = Sm + tid * 8;
    gl_lds16(kp, kb);
    gl_lds16(kp + 32 * H3, kb + 2048);
    gl_lds16(vp, kb + 8192);
    gl_lds16(vp + 32 * SB, kb + 8192 + 2048);
  }

#define QKK(BUFB, kk)                                                              \
      { bhalf8 ka = *(const bhalf8*)(LB + (BUFB) + koff[2*(kk)]);                  \
        s0 = __builtin_amdgcn_mfma_f32_32x32x16_bf16(ka, qf[kk], s0, 0, 0, 0);     \
        bhalf8 kb2 = *(const bhalf8*)(LB + (BUFB) + koff[2*(kk)+1]);               \
        s1 = __builtin_amdgcn_mfma_f32_32x32x16_bf16(kb2, qf[kk], s1, 0, 0, 0); }
#define PVC(BUFB, c, pfv)                                                          \
      { bhalf8 va = *(const bhalf8*)(LB + 16384 + (BUFB) + koff[2*(c)]);           \
        acc0 = __builtin_amdgcn_mfma_f32_32x32x16_bf16(va, pfv, acc0, 0, 0, 0);    \
        bhalf8 vb2 = *(const bhalf8*)(LB + 16384 + (BUFB) + koff[2*(c)+1]);        \
        acc1 = __builtin_amdgcn_mfma_f32_32x32x16_bf16(vb2, pfv, acc1, 0, 0, 0); }
#define MSK0(r) { if (k0 + (((r)&3) + 8*((r)>>2)) + 4*hi > qg)      s0[r] = -3.0e38f; }
#define MSK1(r) { if (k0 + 32 + (((r)&3) + 8*((r)>>2)) + 4*hi > qg) s1[r] = -3.0e38f; }
#define PEXP(r) { s0[r] = EXP2(s0[r]); s1[r] = EXP2(s1[r]); rsx[(r)&3] += s0[r] + s1[r]; }
  union PW { int i[4]; bhalf8 v; };
#define PACK2(dst, sv, rb)                                               \
      { int A0 = pkbf(sv[rb + 0], sv[rb + 1]);                           \
        int A1 = pkbf(sv[rb + 2], sv[rb + 3]);                           \
        int B0 = pkbf(sv[rb + 4], sv[rb + 5]);                           \
        int B1 = pkbf(sv[rb + 6], sv[rb + 7]);                           \
        auto r0 = __builtin_amdgcn_permlane32_swap(A0, B0, false, false);\
        auto r1 = __builtin_amdgcn_permlane32_swap(A1, B1, false, false);\
        PW u;                                                            \
        u.i[0] = r0[0]; u.i[1] = r1[0];                                  \
        u.i[2] = r0[1]; u.i[3] = r1[1];                                  \
        dst = u.v; }

#define FLASH_COMPUTE(BUFB)                                                        \
    { floatx16 s0 = Z16, s1 = Z16;                                                 \
      __builtin_amdgcn_s_setprio(1);                                               \
      QKK(BUFB, 0) QKK(BUFB, 1) QKK(BUFB, 2) QKK(BUFB, 3)                          \
      __builtin_amdgcn_s_setprio(0);                                               \
      if (k0 + 63 > wq0) { REP16(MSK0) REP16(MSK1) }                               \
      float rsx[4] = {0.f, 0.f, 0.f, 0.f};                                         \
      REP16(PEXP)                                                                  \
      l_half += (rsx[0] + rsx[1]) + (rsx[2] + rsx[3]);                             \
      bhalf8 pf0, pf1, pf2, pf3;                                                   \
      PACK2(pf0, s0, 0) PACK2(pf1, s0, 8) PACK2(pf2, s1, 0) PACK2(pf3, s1, 8)      \
      __builtin_amdgcn_s_setprio(1);                                               \
      PVC(BUFB, 0, pf0) PVC(BUFB, 1, pf1) PVC(BUFB, 2, pf2) PVC(BUFB, 3, pf3)      \
      __builtin_amdgcn_s_setprio(0); }

#define DO_STEP(T, BUF)                                                            \
  { __syncthreads();                                                               \
    if ((T) + 1 < nt) {                                                            \
      kp += 64 * H3; vp += 64;                                                     \
      unsigned short* kb = Sm + (1 - (BUF)) * 4096 + tid * 8;                      \
      gl_lds16(kp, kb); gl_lds16(kp + 32 * H3, kb + 2048);                         \
      gl_lds16(vp, kb + 8192); gl_lds16(vp + 32 * SB, kb + 8192 + 2048);           \
    }                                                                              \
    const int k0 = (T) * 64;                                                       \
    if (k0 <= wq0 + 31) FLASH_COMPUTE((BUF) * 8192)                                \
  }

  for (int t = 0; t < nt; t += 2) {
    DO_STEP(t, 0)
    DO_STEP(t + 1, 1)
  }

  const float l_full = l_half + __shfl_xor(l_half, 32);
  const float inv_l = 1.f / l_full;
  unsigned short* op = outp + (rowbase + qg) * HB + h * 64;
#pragma unroll
  for (int tq = 0; tq < 4; ++tq) {
    ushort4 st;
    st.x = f2bf(acc0[4 * tq + 0] * inv_l);
    st.y = f2bf(acc0[4 * tq + 1] * inv_l);
    st.z = f2bf(acc0[4 * tq + 2] * inv_l);
    st.w = f2bf(acc0[4 * tq + 3] * inv_l);
    *(ushort4*)(op + 8 * tq + 4 * hi) = st;
    ushort4 su;
    su.x = f2bf(acc1[4 * tq + 0] * inv_l);
    su.y = f2bf(acc1[4 * tq + 1] * inv_l);
    su.z = f2bf(acc1[4 * tq + 2] * inv_l);
    su.w = f2bf(acc1[4 * tq + 3] * inv_l);
    *(ushort4*)(op + 32 + 8 * tq + 4 * hi) = su;
  }
}

extern "C" void kernel_launch(void* const* d_in, const int* in_sizes, int n_in,
                              void* d_out, int out_size, void* d_ws, size_t ws_size,
                              hipStream_t stream) {
  const float* x      = (const float*)d_in[0];   // [4,2048,1024]
  const float* W_attn = (const float*)d_in[1];   // [1024,3072]
  const float* b_attn = (const float*)d_in[2];   // [3072]
  const float* W_proj = (const float*)d_in[3];   // [1024,1024]
  const float* b_proj = (const float*)d_in[4];   // [1024]
  float* out = (float*)d_out;                    // [4,2048,1024] f32

  char* ws = (char*)d_ws;
  unsigned short* x_bf    = (unsigned short*)(ws);                 // 16777216 B
  unsigned short* Wt_attn = (unsigned short*)(ws + 16777216);      //  6291456 B
  unsigned short* Wt_proj = (unsigned short*)(ws + 23068672);      //  2097152 B
  unsigned short* qkv     = (unsigned short*)(ws + 25165824);      // 50331648 B
  unsigned short* attn    = (unsigned short*)(ws + 75497472);      // 16777216 B
  // Fused path: Vt gets its own region (x_bf is LIVE during the qkv GEMM).
  // Fallback: Vt aliases x_bf and uses the transpose_v kernel.
  const bool fuse = ws_size >= (size_t)92274688 + 16777216;
  unsigned short* VtF = (unsigned short*)(ws + 92274688);
  unsigned short* Vt  = fuse ? VtF : x_bf;

  cvt_f32_bf16<<<8192, 256, 0, stream>>>(x, x_bf, 8192 * 1024);
  transpose_cvt<<<dim3(96, 32), dim3(32, 8), 0, stream>>>(W_attn, Wt_attn, 1024, 3072);
  transpose_cvt<<<dim3(32, 32), dim3(32, 8), 0, stream>>>(W_proj, Wt_proj, 1024, 1024);

  // qkv = x @ W_attn + b_attn (bf16 out) — grid 8x32 = 256 = 1/CU exact
  if (fuse) {
    gemm_v9<true><<<dim3(8, 32), 512, 0, stream>>>(x_bf, Wt_attn, b_attn, qkv, VtF,
                                                   8192, 3072, 1024);
  } else {
    gemm_v9<false><<<dim3(8, 32), 512, 0, stream>>>(x_bf, Wt_attn, b_attn, qkv, nullptr,
                                                    8192, 3072, 1024);
    transpose_v<<<dim3(64, 2, 64), dim3(32, 8), 0, stream>>>(qkv, Vt);
  }
  // flash attention -> attn[8192][1024] (merged heads)
  flash_attn4<<<dim3(64, 16), 256, 0, stream>>>(qkv, Vt, attn);
  // out = attn @ W_proj + b_proj (f32 out) — grid 8x32 = 256 (%8==0)
  gemm_v6<true><<<dim3(8, 32), 512, 0, stream>>>(attn, Wt_proj, b_proj, out,
                                                 8192, 1024, 1024);
}

// Round 16
// 146.362 us; speedup vs baseline: 1.1494x; 1.1494x over previous
//
#include <hip/hip_runtime.h>
#include <hip/hip_bf16.h>

// Fused causal MHA block for MI355X (gfx950).
// B=4 S=2048 H=1024 NH=16 DK=64. Inputs f32; compute in bf16 MFMA (f32 accum).
// Pipeline: cvt(x) | transpose-cvt(W) | GEMM qkv (2-barrier ring-3, scatter
// FUSEV) | flash v4 (256,4) | GEMM proj. Exact restore of the best-measured
// configuration (R10: 145.9us). R14's (256,5) bound forced VGPR 84->48 spill
// (flash 40->86us) — occupancy hints must never cap VGPR below register need.

typedef __attribute__((ext_vector_type(8))) short bhalf8;    // 8 bf16 = 4 VGPRs
typedef __attribute__((ext_vector_type(4))) float floatx4;   // MFMA 16x16 accum
typedef __attribute__((ext_vector_type(16))) float floatx16; // MFMA 32x32 accum

#define SB 2048
#define HB 1024
#define H3 3072

#if __has_builtin(__builtin_amdgcn_exp2f)
#define EXP2(x) __builtin_amdgcn_exp2f(x)
#else
#define EXP2(x) exp2f(x)
#endif

__device__ __forceinline__ float bf2f(unsigned short u) {
  union { unsigned int i; float f; } c; c.i = ((unsigned int)u) << 16; return c.f;
}
__device__ __forceinline__ unsigned short f2bf(float f) {
  union { float f; unsigned int i; } c; c.f = f;
  unsigned int r = c.i + 0x7fffu + ((c.i >> 16) & 1u);   // RNE
  return (unsigned short)(r >> 16);
}
__device__ __forceinline__ int pkbf(float lo, float hi_) {
  union { __hip_bfloat162 h; int i; } u;
  u.h = __float22bfloat162_rn(make_float2(lo, hi_));  // lo -> bits 0..15
  return u.i;
}

// async global->LDS, 16B per lane (dest must be uniform-base + lane*16).
__device__ __forceinline__ void gl_lds16(const unsigned short* g, unsigned short* l) {
  __builtin_amdgcn_global_load_lds(
      (const __attribute__((address_space(1))) unsigned int*)g,
      (__attribute__((address_space(3))) unsigned int*)l, 16, 0, 0);
}

#define REP16(OP) OP(0) OP(1) OP(2) OP(3) OP(4) OP(5) OP(6) OP(7) \
                  OP(8) OP(9) OP(10) OP(11) OP(12) OP(13) OP(14) OP(15)

// ---------------- elementwise f32 -> bf16 ----------------
__global__ void cvt_f32_bf16(const float* __restrict__ in, unsigned short* __restrict__ out, int n) {
  int i = (blockIdx.x * blockDim.x + threadIdx.x) * 4;
  if (i >= n) return;
  float4 v = *(const float4*)(in + i);
  ushort4 o;
  o.x = f2bf(v.x); o.y = f2bf(v.y); o.z = f2bf(v.z); o.w = f2bf(v.w);
  *(ushort4*)(out + i) = o;
}

// ---------------- W[K][N] f32 -> Wt[N][K] bf16 (tiled transpose) ----------------
__global__ void transpose_cvt(const float* __restrict__ in, unsigned short* __restrict__ out,
                              int K, int N) {
  __shared__ float tile[32][33];
  int n0 = blockIdx.x * 32, k0 = blockIdx.y * 32;
  for (int i = threadIdx.y; i < 32; i += 8)
    tile[i][threadIdx.x] = in[(size_t)(k0 + i) * N + n0 + threadIdx.x];
  __syncthreads();
  for (int i = threadIdx.y; i < 32; i += 8)
    out[(size_t)(n0 + i) * K + k0 + threadIdx.x] = f2bf(tile[threadIdx.x][i]);
}

// ---------------- V part of qkv -> Vt[bh*64+dk][S] (fallback path only) ----------------
__global__ void transpose_v(const unsigned short* __restrict__ qkv,
                            unsigned short* __restrict__ Vt) {
  __shared__ unsigned short tile[32][33];
  const int bh = blockIdx.z;
  const int b = bh >> 4, h = bh & 15;
  const int s0 = blockIdx.x * 32;
  const int d0 = blockIdx.y * 32;
  const int tx = threadIdx.x;
  const unsigned short* src = qkv + (size_t)(b * SB + s0) * H3 + 2 * HB + h * 64 + d0;
  for (int i = threadIdx.y; i < 32; i += 8)
    tile[i][tx] = src[(size_t)i * H3 + tx];
  __syncthreads();
  unsigned short* dst = Vt + ((size_t)bh * 64 + d0) * SB + s0;
  for (int i = threadIdx.y; i < 32; i += 8)
    dst[(size_t)i * SB + tx] = tile[tx][i];
}

// ---------------- GEMM (qkv): C[M=8192][N=3072] = A @ Bt^T + bias, bf16 out ----
// BM=256 BN=384 BK=32. 512 thr = 8 waves (2Mx4N), wave tile 128x96 (acc 8x6).
// Ring-3 slots of 40KB; 5 gl_lds16/thread/tile staged 2 ahead; vmcnt(5) at tile
// top; 2 barriers/tile. FUSEV: V cols (>=2048) scatter-stored to Vt.
template <bool FUSEV>
__global__ __launch_bounds__(512, 2) void gemm_v9(
    const unsigned short* __restrict__ A,
    const unsigned short* __restrict__ Bt,
    const float* __restrict__ bias,
    unsigned short* __restrict__ C,
    unsigned short* __restrict__ Vt,
    int M, int N, int K) {
  __shared__ __align__(16) unsigned short Sm[3 * 20480];   // 122880 B
  const int tid = threadIdx.x;
  const int lane = tid & 63;
  const int w = tid >> 6;
  const int l15 = lane & 15, l4 = lane >> 4;
  const int wm = w >> 2, wn = w & 3;

  // bijective XCD swizzle (grid = 256, %8==0)
  const int gx = gridDim.x;               // 8
  int lin = blockIdx.y * gx + blockIdx.x;
  const int cpx = (gx * gridDim.y) >> 3;
  lin = (lin & 7) * cpx + (lin >> 3);
  const int m0 = (lin / gx) * 256;
  const int n0 = (lin % gx) * 384;

  const int rb0 = tid >> 2;
  const int co = (((tid & 3) ^ ((tid >> 3) & 3)) * 8);
  const unsigned short* pA0 = A + (size_t)(m0 + rb0) * K + co;
  const unsigned short* pA1 = pA0 + (size_t)128 * K;
  const unsigned short* pB0 = Bt + (size_t)(n0 + rb0) * K + co;
  const unsigned short* pB1 = pB0 + (size_t)128 * K;
  const unsigned short* pB2 = pB0 + (size_t)256 * K;

  const int ra0 = wm * 128 + l15;
  const int ab0 = ra0 * 64 + ((l4 ^ ((ra0 >> 1) & 3)) << 4);
  const int rbq = wn * 96 + l15;
  const int bb0 = 16384 + rbq * 64 + ((l4 ^ ((rbq >> 1) & 3)) << 4);

  const floatx4 zero = {0.f, 0.f, 0.f, 0.f};
  floatx4 acc[8][6];
#pragma unroll
  for (int i = 0; i < 8; ++i)
#pragma unroll
    for (int j = 0; j < 6; ++j) acc[i][j] = zero;

#define STAGE_A(k0, ss)                                                 \
  { gl_lds16(pA0 + (k0), Sm + (ss) + tid * 8);                          \
    gl_lds16(pA1 + (k0), Sm + (ss) + (tid + 512) * 8); }
#define STAGE_B(k0, ss)                                                 \
  { gl_lds16(pB0 + (k0), Sm + (ss) + 8192 + tid * 8);                   \
    gl_lds16(pB1 + (k0), Sm + (ss) + 8192 + (tid + 512) * 8);           \
    gl_lds16(pB2 + (k0), Sm + (ss) + 8192 + (tid + 1024) * 8); }

  const int NT = K >> 5;                  // 32
  STAGE_A(0, 0)      STAGE_B(0, 0)
  STAGE_A(32, 20480) STAGE_B(32, 20480)
  int sb = 0;
  int ss = 40960;

  for (int t = 0; t < NT; ++t) {
    if (t < NT - 1) asm volatile("s_waitcnt vmcnt(5)" ::: "memory");
    else            asm volatile("s_waitcnt vmcnt(0)" ::: "memory");
    __builtin_amdgcn_s_barrier();   // top barrier: tile t resident; orders slot reuse.

    const char* LB = (const char*)(Sm + sb);
    const int k2 = (t + 2) * 32;
    const bool st = (t + 2 < NT);

    // ---- phase 1: A0..A3 x B0..B5 ----
    bhalf8 a0 = *(const bhalf8*)(LB + ab0);
    bhalf8 a1 = *(const bhalf8*)(LB + ab0 + 1024);
    bhalf8 a2 = *(const bhalf8*)(LB + ab0 + 2048);
    bhalf8 a3 = *(const bhalf8*)(LB + ab0 + 3072);
    bhalf8 b0 = *(const bhalf8*)(LB + bb0);
    bhalf8 b1 = *(const bhalf8*)(LB + bb0 + 1024);
    bhalf8 b2 = *(const bhalf8*)(LB + bb0 + 2048);
    bhalf8 b3 = *(const bhalf8*)(LB + bb0 + 3072);
    bhalf8 b4 = *(const bhalf8*)(LB + bb0 + 4096);
    bhalf8 b5 = *(const bhalf8*)(LB + bb0 + 5120);
    if (st) STAGE_A(k2, ss)
    __builtin_amdgcn_s_setprio(1);
#define MROW(i, av)                                                              \
    acc[i][0] = __builtin_amdgcn_mfma_f32_16x16x32_bf16(av, b0, acc[i][0], 0, 0, 0); \
    acc[i][1] = __builtin_amdgcn_mfma_f32_16x16x32_bf16(av, b1, acc[i][1], 0, 0, 0); \
    acc[i][2] = __builtin_amdgcn_mfma_f32_16x16x32_bf16(av, b2, acc[i][2], 0, 0, 0); \
    acc[i][3] = __builtin_amdgcn_mfma_f32_16x16x32_bf16(av, b3, acc[i][3], 0, 0, 0); \
    acc[i][4] = __builtin_amdgcn_mfma_f32_16x16x32_bf16(av, b4, acc[i][4], 0, 0, 0); \
    acc[i][5] = __builtin_amdgcn_mfma_f32_16x16x32_bf16(av, b5, acc[i][5], 0, 0, 0);
    MROW(0, a0) MROW(1, a1) MROW(2, a2) MROW(3, a3)
    __builtin_amdgcn_s_setprio(0);
    __builtin_amdgcn_s_barrier();          // mid-tile lockstep

    // ---- phase 2: A4..A7 x B0..B5 ----
    bhalf8 a4 = *(const bhalf8*)(LB + ab0 + 4096);
    bhalf8 a5 = *(const bhalf8*)(LB + ab0 + 5120);
    bhalf8 a6 = *(const bhalf8*)(LB + ab0 + 6144);
    bhalf8 a7 = *(const bhalf8*)(LB + ab0 + 7168);
    if (st) STAGE_B(k2, ss)
    __builtin_amdgcn_s_setprio(1);
    MROW(4, a4) MROW(5, a5) MROW(6, a6) MROW(7, a7)
#undef MROW
    __builtin_amdgcn_s_setprio(0);
    // no end barrier: next iteration's top barrier orders slot reuse (ring-3).

    sb = (sb == 40960) ? 0 : sb + 20480;
    ss = (ss == 40960) ? 0 : ss + 20480;
  }
#undef STAGE_A
#undef STAGE_B

#pragma unroll
  for (int i = 0; i < 8; ++i) {
    int row = m0 + wm * 128 + i * 16 + (l4 << 2);
#pragma unroll
    for (int j = 0; j < 6; ++j) {
      int col = n0 + wn * 96 + j * 16 + l15;
      float bb = bias[col];
      if (!FUSEV || col < 2048) {
#pragma unroll
        for (int r = 0; r < 4; ++r)
          C[(size_t)(row + r) * N + col] = f2bf(acc[i][j][r] + bb);
      } else {
        // V section: scatter to per-head transposed Vt[(b*16+h)*64+dk][s]
        int vc = col - 2048;
        int h2 = vc >> 6, dk = vc & 63;
        int b2 = row >> 11, s = row & 2047;
        ushort4 pv;
        pv.x = f2bf(acc[i][j][0] + bb);
        pv.y = f2bf(acc[i][j][1] + bb);
        pv.z = f2bf(acc[i][j][2] + bb);
        pv.w = f2bf(acc[i][j][3] + bb);
        *(ushort4*)(Vt + ((size_t)((b2 * 16 + h2) * 64 + dk)) * SB + s) = pv;
      }
    }
  }
}

// ---------------- GEMM v6 (proj): C = A @ Bt^T + bias ----------------
// BM=256 BN=128 BK=32. 512 thr = 8 waves (4Mx2N, 64x64). Ring-3, 2 barriers/tile.
template <bool F32OUT>
__global__ __launch_bounds__(512, 4) void gemm_v6(
    const unsigned short* __restrict__ A,
    const unsigned short* __restrict__ Bt,
    const float* __restrict__ bias,
    void* __restrict__ Cv,
    int M, int N, int K) {
  __shared__ __align__(16) unsigned short Sm[3 * 12288];   // 73728 B
  const int tid = threadIdx.x;
  const int lane = tid & 63;
  const int w = tid >> 6;
  const int l15 = lane & 15, l4 = lane >> 4;
  const int wr = (w >> 1) * 64;
  const int wc = (w & 1) * 64;

  const int gx = gridDim.x;
  int lin = blockIdx.y * gx + blockIdx.x;
  const int cpx = (gx * gridDim.y) >> 3;
  lin = (lin & 7) * cpx + (lin >> 3);
  const int m0 = (lin / gx) * 256;
  const int n0 = (lin % gx) * 128;

  const int idx0 = tid, idx1 = tid + 512;
  const unsigned short* pA0 = A + (size_t)(m0 + (idx0 >> 2)) * K + (((idx0 & 3) ^ ((idx0 >> 3) & 3)) * 8);
  const unsigned short* pA1 = A + (size_t)(m0 + (idx1 >> 2)) * K + (((idx1 & 3) ^ ((idx1 >> 3) & 3)) * 8);
  const unsigned short* pB  = Bt + (size_t)(n0 + (tid >> 2)) * K + (((tid & 3) ^ ((tid >> 3) & 3)) * 8);

  int abyte[4], bbyte[4];
#pragma unroll
  for (int i = 0; i < 4; ++i) {
    int ra = wr + i * 16 + l15;
    abyte[i] = ra * 64 + ((l4 ^ ((ra >> 1) & 3)) << 4);
    int rb = wc + i * 16 + l15;
    bbyte[i] = 16384 + rb * 64 + ((l4 ^ ((rb >> 1) & 3)) << 4);
  }

  const floatx4 zero = {0.f, 0.f, 0.f, 0.f};
  floatx4 acc[4][4];
#pragma unroll
  for (int i = 0; i < 4; ++i)
#pragma unroll
    for (int j = 0; j < 4; ++j) acc[i][j] = zero;

#define STAGE_A6(k0, sbase)                                             \
  { gl_lds16(pA0 + (k0), Sm + (sbase) + idx0 * 8);                      \
    gl_lds16(pA1 + (k0), Sm + (sbase) + idx1 * 8); }
#define STAGE_B6(k0, sbase)                                             \
  { gl_lds16(pB + (k0), Sm + (sbase) + 8192 + tid * 8); }

  const int NT = K >> 5;
  STAGE_A6(0, 0)  STAGE_B6(0, 0)
  STAGE_A6(32, 12288) STAGE_B6(32, 12288)
  int sb = 0;
  int ss = 24576;

  for (int t = 0; t < NT; ++t) {
    if (t < NT - 1) asm volatile("s_waitcnt vmcnt(3)" ::: "memory");
    else            asm volatile("s_waitcnt vmcnt(0)" ::: "memory");
    __builtin_amdgcn_s_barrier();

    const char* LB = (const char*)(Sm + sb);
    const int k2 = (t + 2) * 32;
    const bool st = (t + 2 < NT);

    bhalf8 a0 = *(const bhalf8*)(LB + abyte[0]);
    bhalf8 a1 = *(const bhalf8*)(LB + abyte[1]);
    bhalf8 b0 = *(const bhalf8*)(LB + bbyte[0]);
    bhalf8 b1 = *(const bhalf8*)(LB + bbyte[1]);
    bhalf8 b2 = *(const bhalf8*)(LB + bbyte[2]);
    bhalf8 b3 = *(const bhalf8*)(LB + bbyte[3]);
    if (st) STAGE_A6(k2, ss)
    __builtin_amdgcn_s_setprio(1);
    acc[0][0] = __builtin_amdgcn_mfma_f32_16x16x32_bf16(a0, b0, acc[0][0], 0, 0, 0);
    acc[0][1] = __builtin_amdgcn_mfma_f32_16x16x32_bf16(a0, b1, acc[0][1], 0, 0, 0);
    acc[0][2] = __builtin_amdgcn_mfma_f32_16x16x32_bf16(a0, b2, acc[0][2], 0, 0, 0);
    acc[0][3] = __builtin_amdgcn_mfma_f32_16x16x32_bf16(a0, b3, acc[0][3], 0, 0, 0);
    acc[1][0] = __builtin_amdgcn_mfma_f32_16x16x32_bf16(a1, b0, acc[1][0], 0, 0, 0);
    acc[1][1] = __builtin_amdgcn_mfma_f32_16x16x32_bf16(a1, b1, acc[1][1], 0, 0, 0);
    acc[1][2] = __builtin_amdgcn_mfma_f32_16x16x32_bf16(a1, b2, acc[1][2], 0, 0, 0);
    acc[1][3] = __builtin_amdgcn_mfma_f32_16x16x32_bf16(a1, b3, acc[1][3], 0, 0, 0);
    __builtin_amdgcn_s_setprio(0);
    __builtin_amdgcn_s_barrier();          // mid-tile lockstep

    bhalf8 a2 = *(const bhalf8*)(LB + abyte[2]);
    bhalf8 a3 = *(const bhalf8*)(LB + abyte[3]);
    if (st) STAGE_B6(k2, ss)
    __builtin_amdgcn_s_setprio(1);
    acc[2][0] = __builtin_amdgcn_mfma_f32_16x16x32_bf16(a2, b0, acc[2][0], 0, 0, 0);
    acc[2][1] = __builtin_amdgcn_mfma_f32_16x16x32_bf16(a2, b1, acc[2][1], 0, 0, 0);
    acc[2][2] = __builtin_amdgcn_mfma_f32_16x16x32_bf16(a2, b2, acc[2][2], 0, 0, 0);
    acc[2][3] = __builtin_amdgcn_mfma_f32_16x16x32_bf16(a2, b3, acc[2][3], 0, 0, 0);
    acc[3][0] = __builtin_amdgcn_mfma_f32_16x16x32_bf16(a3, b0, acc[3][0], 0, 0, 0);
    acc[3][1] = __builtin_amdgcn_mfma_f32_16x16x32_bf16(a3, b1, acc[3][1], 0, 0, 0);
    acc[3][2] = __builtin_amdgcn_mfma_f32_16x16x32_bf16(a3, b2, acc[3][2], 0, 0, 0);
    acc[3][3] = __builtin_amdgcn_mfma_f32_16x16x32_bf16(a3, b3, acc[3][3], 0, 0, 0);
    __builtin_amdgcn_s_setprio(0);
    // no end barrier (ring-3 ordering via next top barrier)

    sb = (sb == 24576) ? 0 : sb + 12288;
    ss = (ss == 24576) ? 0 : ss + 12288;
  }
#undef STAGE_A6
#undef STAGE_B6

  float* Cf = (float*)Cv;
  unsigned short* Cb = (unsigned short*)Cv;
#pragma unroll
  for (int i = 0; i < 4; ++i) {
    int row = m0 + wr + i * 16 + (l4 << 2);
#pragma unroll
    for (int j = 0; j < 4; ++j) {
      int col = n0 + wc + j * 16 + l15;
      float bb = bias[col];
#pragma unroll
      for (int r = 0; r < 4; ++r) {
        float v = acc[i][j][r] + bb;
        size_t idx = (size_t)(row + r) * N + col;
        if constexpr (F32OUT) Cf[idx] = v;
        else Cb[idx] = f2bf(v);
      }
    }
  }
}

// ---------------- flash attention v4 (R10 config: launch_bounds(256,4)) ----------------
__global__ __launch_bounds__(256, 4) void flash_attn4(
    const unsigned short* __restrict__ qkv,   // [B*S][3H] bf16
    const unsigned short* __restrict__ Vt,    // [bh*64+dk][S] bf16
    unsigned short* __restrict__ outp) {      // [B*S][H]  bf16
  __shared__ __align__(16) unsigned short Sm[4 * 4096];

  const int tid = threadIdx.x;
  const int lane = tid & 63;
  const int w = tid >> 6;
  const int hi = lane >> 5;
  const int qc = lane & 31;
  const int bh = blockIdx.x;
  const int b = bh >> 4, h = bh & 15;
  const int qt = 15 - (int)blockIdx.y;   // big tiles dispatch first
  const int wq0 = qt * 128 + w * 32;
  const size_t rowbase = (size_t)b * SB;
  const int qg = wq0 + qc;
  const int nt = 2 * qt + 2;             // always even

  bhalf8 qf[4];
  {
    const unsigned short* qp = qkv + (rowbase + qg) * H3 + h * 64 + hi * 8;
#pragma unroll
    for (int kk = 0; kk < 4; ++kk) {
      bhalf8 v = *(const bhalf8*)(qp + kk * 16);
      bhalf8 o;
#pragma unroll
      for (int j = 0; j < 8; ++j)
        o[j] = (short)f2bf(bf2f((unsigned short)v[j]) * 0.18033688f);
      qf[kk] = o;
    }
  }

  const floatx16 Z16 = {0,0,0,0,0,0,0,0,0,0,0,0,0,0,0,0};
  floatx16 acc0 = Z16, acc1 = Z16;   // O^T: col q=qc, rows dk
  float l_half = 0.f;

  const char* LB = (const char*)Sm;
  int koff[8];
#pragma unroll
  for (int kk = 0; kk < 4; ++kk) {
    int xo = (((2 * kk + hi) ^ (qc & 7)) << 4);
    koff[2 * kk]     = qc * 128 + xo;
    koff[2 * kk + 1] = (32 + qc) * 128 + xo;
  }

  const int srow = tid >> 3, schk = tid & 7;
  const int sxe = (schk ^ (srow & 7)) * 8;
  const unsigned short* kp = qkv + (rowbase + srow) * H3 + HB + h * 64 + sxe;
  const unsigned short* vp = Vt + ((size_t)bh * 64 + srow) * SB + sxe;

  {
    unsigned short* kb = Sm + tid * 8;
    gl_lds16(kp, kb);
    gl_lds16(kp + 32 * H3, kb + 2048);
    gl_lds16(vp, kb + 8192);
    gl_lds16(vp + 32 * SB, kb + 8192 + 2048);
  }

#define QKK(BUFB, kk)                                                              \
      { bhalf8 ka = *(const bhalf8*)(LB + (BUFB) + koff[2*(kk)]);                  \
        s0 = __builtin_amdgcn_mfma_f32_32x32x16_bf16(ka, qf[kk], s0, 0, 0, 0);     \
        bhalf8 kb2 = *(const bhalf8*)(LB + (BUFB) + koff[2*(kk)+1]);               \
        s1 = __builtin_amdgcn_mfma_f32_32x32x16_bf16(kb2, qf[kk], s1, 0, 0, 0); }
#define PVC(BUFB, c, pfv)                                                          \
      { bhalf8 va = *(const bhalf8*)(LB + 16384 + (BUFB) + koff[2*(c)]);           \
        acc0 = __builtin_amdgcn_mfma_f32_32x32x16_bf16(va, pfv, acc0, 0, 0, 0);    \
        bhalf8 vb2 = *(const bhalf8*)(LB + 16384 + (BUFB) + koff[2*(c)+1]);        \
        acc1 = __builtin_amdgcn_mfma_f32_32x32x16_bf16(vb2, pfv, acc1, 0, 0, 0); }
#define MSK0(r) { if (k0 + (((r)&3) + 8*((r)>>2)) + 4*hi > qg)      s0[r] = -3.0e38f; }
#define MSK1(r) { if (k0 + 32 + (((r)&3) + 8*((r)>>2)) + 4*hi > qg) s1[r] = -3.0e38f; }
#define PEXP(r) { s0[r] = EXP2(s0[r]); s1[r] = EXP2(s1[r]); rsx[(r)&3] += s0[r] + s1[r]; }
  union PW { int i[4]; bhalf8 v; };
#define PACK2(dst, sv, rb)                                               \
      { int A0 = pkbf(sv[rb + 0], sv[rb + 1]);                           \
        int A1 = pkbf(sv[rb + 2], sv[rb + 3]);                           \
        int B0 = pkbf(sv[rb + 4], sv[rb + 5]);                           \
        int B1 = pkbf(sv[rb + 6], sv[rb + 7]);                           \
        auto r0 = __builtin_amdgcn_permlane32_swap(A0, B0, false, false);\
        auto r1 = __builtin_amdgcn_permlane32_swap(A1, B1, false, false);\
        PW u;                                                            \
        u.i[0] = r0[0]; u.i[1] = r1[0];                                  \
        u.i[2] = r0[1]; u.i[3] = r1[1];                                  \
        dst = u.v; }

#define FLASH_COMPUTE(BUFB)                                                        \
    { floatx16 s0 = Z16, s1 = Z16;                                                 \
      __builtin_amdgcn_s_setprio(1);                                               \
      QKK(BUFB, 0) QKK(BUFB, 1) QKK(BUFB, 2) QKK(BUFB, 3)                          \
      __builtin_amdgcn_s_setprio(0);                                               \
      if (k0 + 63 > wq0) { REP16(MSK0) REP16(MSK1) }                               \
      float rsx[4] = {0.f, 0.f, 0.f, 0.f};                                         \
      REP16(PEXP)                                                                  \
      l_half += (rsx[0] + rsx[1]) + (rsx[2] + rsx[3]);                             \
      bhalf8 pf0, pf1, pf2, pf3;                                                   \
      PACK2(pf0, s0, 0) PACK2(pf1, s0, 8) PACK2(pf2, s1, 0) PACK2(pf3, s1, 8)      \
      __builtin_amdgcn_s_setprio(1);                                               \
      PVC(BUFB, 0, pf0) PVC(BUFB, 1, pf1) PVC(BUFB, 2, pf2) PVC(BUFB, 3, pf3)      \
      __builtin_amdgcn_s_setprio(0); }

#define DO_STEP(T, BUF)                                                            \
  { __syncthreads();                                                               \
    if ((T) + 1 < nt) {                                                            \
      kp += 64 * H3; vp += 64;                                                     \
      unsigned short* kb = Sm + (1 - (BUF)) * 4096 + tid * 8;                      \
      gl_lds16(kp, kb); gl_lds16(kp + 32 * H3, kb + 2048);                         \
      gl_lds16(vp, kb + 8192); gl_lds16(vp + 32 * SB, kb + 8192 + 2048);           \
    }                                                                              \
    const int k0 = (T) * 64;                                                       \
    if (k0 <= wq0 + 31) FLASH_COMPUTE((BUF) * 8192)                                \
  }

  for (int t = 0; t < nt; t += 2) {
    DO_STEP(t, 0)
    DO_STEP(t + 1, 1)
  }

  const float l_full = l_half + __shfl_xor(l_half, 32);
  const float inv_l = 1.f / l_full;
  unsigned short* op = outp + (rowbase + qg) * HB + h * 64;
#pragma unroll
  for (int tq = 0; tq < 4; ++tq) {
    ushort4 st;
    st.x = f2bf(acc0[4 * tq + 0] * inv_l);
    st.y = f2bf(acc0[4 * tq + 1] * inv_l);
    st.z = f2bf(acc0[4 * tq + 2] * inv_l);
    st.w = f2bf(acc0[4 * tq + 3] * inv_l);
    *(ushort4*)(op + 8 * tq + 4 * hi) = st;
    ushort4 su;
    su.x = f2bf(acc1[4 * tq + 0] * inv_l);
    su.y = f2bf(acc1[4 * tq + 1] * inv_l);
    su.z = f2bf(acc1[4 * tq + 2] * inv_l);
    su.w = f2bf(acc1[4 * tq + 3] * inv_l);
    *(ushort4*)(op + 32 + 8 * tq + 4 * hi) = su;
  }
}

extern "C" void kernel_launch(void* const* d_in, const int* in_sizes, int n_in,
                              void* d_out, int out_size, void* d_ws, size_t ws_size,
                              hipStream_t stream) {
  const float* x      = (const float*)d_in[0];   // [4,2048,1024]
  const float* W_attn = (const float*)d_in[1];   // [1024,3072]
  const float* b_attn = (const float*)d_in[2];   // [3072]
  const float* W_proj = (const float*)d_in[3];   // [1024,1024]
  const float* b_proj = (const float*)d_in[4];   // [1024]
  float* out = (float*)d_out;                    // [4,2048,1024] f32

  char* ws = (char*)d_ws;
  unsigned short* x_bf    = (unsigned short*)(ws);                 // 16777216 B
  unsigned short* Wt_attn = (unsigned short*)(ws + 16777216);      //  6291456 B
  unsigned short* Wt_proj = (unsigned short*)(ws + 23068672);      //  2097152 B
  unsigned short* qkv     = (unsigned short*)(ws + 25165824);      // 50331648 B
  unsigned short* attn    = (unsigned short*)(ws + 75497472);      // 16777216 B
  // Fused path: Vt gets its own region (x_bf is LIVE during the qkv GEMM).
  // Fallback: Vt aliases x_bf and uses the transpose_v kernel.
  const bool fuse = ws_size >= (size_t)92274688 + 16777216;
  unsigned short* VtF = (unsigned short*)(ws + 92274688);
  unsigned short* Vt  = fuse ? VtF : x_bf;

  cvt_f32_bf16<<<8192, 256, 0, stream>>>(x, x_bf, 8192 * 1024);
  transpose_cvt<<<dim3(96, 32), dim3(32, 8), 0, stream>>>(W_attn, Wt_attn, 1024, 3072);
  transpose_cvt<<<dim3(32, 32), dim3(32, 8), 0, stream>>>(W_proj, Wt_proj, 1024, 1024);

  // qkv = x @ W_attn + b_attn (bf16 out) — grid 8x32 = 256 = 1/CU exact
  if (fuse) {
    gemm_v9<true><<<dim3(8, 32), 512, 0, stream>>>(x_bf, Wt_attn, b_attn, qkv, VtF,
                                                   8192, 3072, 1024);
  } else {
    gemm_v9<false><<<dim3(8, 32), 512, 0, stream>>>(x_bf, Wt_attn, b_attn, qkv, nullptr,
                                                    8192, 3072, 1024);
    transpose_v<<<dim3(64, 2, 64), dim3(32, 8), 0, stream>>>(qkv, Vt);
  }
  // flash attention -> attn[8192][1024] (merged heads)
  flash_attn4<<<dim3(64, 16), 256, 0, stream>>>(qkv, Vt, attn);
  // out = attn @ W_proj + b_proj (f32 out) — grid 8x32 = 256 (%8==0)
  gemm_v6<true><<<dim3(8, 32), 512, 0, stream>>>(attn, Wt_proj, b_proj, out,
                                                 8192, 1024, 1024);
}

// Round 17
// 141.539 us; speedup vs baseline: 1.1886x; 1.0341x over previous
//
#include <hip/hip_runtime.h>
#include <hip/hip_bf16.h>

// Fused causal MHA block for MI355X (gfx950).
// B=4 S=2048 H=1024 NH=16 DK=64. Inputs f32; compute in bf16 MFMA (f32 accum).
// Pipeline: prep_all (fused cvt(x) + transpose-cvt(W_attn) + transpose-cvt(W_proj))
// | GEMM qkv (2-barrier ring-3, scatter FUSEV) | flash v4 (256,4) | GEMM proj.
// R16: merged the 3 prep launches into 1 (range-dispatched 1D grid) to cut
// inter-dispatch gaps; compute kernels byte-identical to the measured-best R10/R15.

typedef __attribute__((ext_vector_type(8))) short bhalf8;    // 8 bf16 = 4 VGPRs
typedef __attribute__((ext_vector_type(4))) float floatx4;   // MFMA 16x16 accum
typedef __attribute__((ext_vector_type(16))) float floatx16; // MFMA 32x32 accum

#define SB 2048
#define HB 1024
#define H3 3072

#if __has_builtin(__builtin_amdgcn_exp2f)
#define EXP2(x) __builtin_amdgcn_exp2f(x)
#else
#define EXP2(x) exp2f(x)
#endif

__device__ __forceinline__ float bf2f(unsigned short u) {
  union { unsigned int i; float f; } c; c.i = ((unsigned int)u) << 16; return c.f;
}
__device__ __forceinline__ unsigned short f2bf(float f) {
  union { float f; unsigned int i; } c; c.f = f;
  unsigned int r = c.i + 0x7fffu + ((c.i >> 16) & 1u);   // RNE
  return (unsigned short)(r >> 16);
}
__device__ __forceinline__ int pkbf(float lo, float hi_) {
  union { __hip_bfloat162 h; int i; } u;
  u.h = __float22bfloat162_rn(make_float2(lo, hi_));  // lo -> bits 0..15
  return u.i;
}

// async global->LDS, 16B per lane (dest must be uniform-base + lane*16).
__device__ __forceinline__ void gl_lds16(const unsigned short* g, unsigned short* l) {
  __builtin_amdgcn_global_load_lds(
      (const __attribute__((address_space(1))) unsigned int*)g,
      (__attribute__((address_space(3))) unsigned int*)l, 16, 0, 0);
}

#define REP16(OP) OP(0) OP(1) OP(2) OP(3) OP(4) OP(5) OP(6) OP(7) \
                  OP(8) OP(9) OP(10) OP(11) OP(12) OP(13) OP(14) OP(15)

// ---------------- fused prep: cvt(x) | W_attn^T | W_proj^T ----------------
// 1D grid of 12288 blocks x 256 thr:
//   [0, 8192)            : x f32 -> bf16, 4 elems/thread
//   [8192, 8192+3072)    : W_attn [1024][3072] -> Wt_attn [3072][1024] (32x32 tiles)
//   [11264, 11264+1024)  : W_proj [1024][1024] -> Wt_proj [1024][1024]
__global__ __launch_bounds__(256) void prep_all(
    const float* __restrict__ x, unsigned short* __restrict__ x_bf,
    const float* __restrict__ Wa, unsigned short* __restrict__ Wat,
    const float* __restrict__ Wp, unsigned short* __restrict__ Wpt) {
  const int bid = blockIdx.x;
  if (bid < 8192) {
    int i = (bid * 256 + threadIdx.x) * 4;
    float4 v = *(const float4*)(x + i);
    ushort4 o;
    o.x = f2bf(v.x); o.y = f2bf(v.y); o.z = f2bf(v.z); o.w = f2bf(v.w);
    *(ushort4*)(x_bf + i) = o;
    return;
  }
  __shared__ float tile[32][33];
  const float* in;
  unsigned short* out;
  int K = 1024, N, n0, k0;
  if (bid < 11264) {
    int tb = bid - 8192;              // 96 x 32 tiles
    N = 3072; in = Wa; out = Wat;
    n0 = (tb % 96) * 32; k0 = (tb / 96) * 32;
  } else {
    int tb = bid - 11264;             // 32 x 32 tiles
    N = 1024; in = Wp; out = Wpt;
    n0 = (tb % 32) * 32; k0 = (tb / 32) * 32;
  }
  const int tx = threadIdx.x & 31, ty = threadIdx.x >> 5;
  for (int i = ty; i < 32; i += 8)
    tile[i][tx] = in[(size_t)(k0 + i) * N + n0 + tx];
  __syncthreads();
  for (int i = ty; i < 32; i += 8)
    out[(size_t)(n0 + i) * K + k0 + tx] = f2bf(tile[tx][i]);
}

// ---------------- V part of qkv -> Vt[bh*64+dk][S] (fallback path only) ----------------
__global__ void transpose_v(const unsigned short* __restrict__ qkv,
                            unsigned short* __restrict__ Vt) {
  __shared__ unsigned short tile[32][33];
  const int bh = blockIdx.z;
  const int b = bh >> 4, h = bh & 15;
  const int s0 = blockIdx.x * 32;
  const int d0 = blockIdx.y * 32;
  const int tx = threadIdx.x;
  const unsigned short* src = qkv + (size_t)(b * SB + s0) * H3 + 2 * HB + h * 64 + d0;
  for (int i = threadIdx.y; i < 32; i += 8)
    tile[i][tx] = src[(size_t)i * H3 + tx];
  __syncthreads();
  unsigned short* dst = Vt + ((size_t)bh * 64 + d0) * SB + s0;
  for (int i = threadIdx.y; i < 32; i += 8)
    dst[(size_t)i * SB + tx] = tile[tx][i];
}

// ---------------- GEMM (qkv): C[M=8192][N=3072] = A @ Bt^T + bias, bf16 out ----
// BM=256 BN=384 BK=32. 512 thr = 8 waves (2Mx4N), wave tile 128x96 (acc 8x6).
// Ring-3 slots of 40KB; 5 gl_lds16/thread/tile staged 2 ahead; vmcnt(5) at tile
// top; 2 barriers/tile. FUSEV: V cols (>=2048) scatter-stored to Vt.
template <bool FUSEV>
__global__ __launch_bounds__(512, 2) void gemm_v9(
    const unsigned short* __restrict__ A,
    const unsigned short* __restrict__ Bt,
    const float* __restrict__ bias,
    unsigned short* __restrict__ C,
    unsigned short* __restrict__ Vt,
    int M, int N, int K) {
  __shared__ __align__(16) unsigned short Sm[3 * 20480];   // 122880 B
  const int tid = threadIdx.x;
  const int lane = tid & 63;
  const int w = tid >> 6;
  const int l15 = lane & 15, l4 = lane >> 4;
  const int wm = w >> 2, wn = w & 3;

  // bijective XCD swizzle (grid = 256, %8==0)
  const int gx = gridDim.x;               // 8
  int lin = blockIdx.y * gx + blockIdx.x;
  const int cpx = (gx * gridDim.y) >> 3;
  lin = (lin & 7) * cpx + (lin >> 3);
  const int m0 = (lin / gx) * 256;
  const int n0 = (lin % gx) * 384;

  const int rb0 = tid >> 2;
  const int co = (((tid & 3) ^ ((tid >> 3) & 3)) * 8);
  const unsigned short* pA0 = A + (size_t)(m0 + rb0) * K + co;
  const unsigned short* pA1 = pA0 + (size_t)128 * K;
  const unsigned short* pB0 = Bt + (size_t)(n0 + rb0) * K + co;
  const unsigned short* pB1 = pB0 + (size_t)128 * K;
  const unsigned short* pB2 = pB0 + (size_t)256 * K;

  const int ra0 = wm * 128 + l15;
  const int ab0 = ra0 * 64 + ((l4 ^ ((ra0 >> 1) & 3)) << 4);
  const int rbq = wn * 96 + l15;
  const int bb0 = 16384 + rbq * 64 + ((l4 ^ ((rbq >> 1) & 3)) << 4);

  const floatx4 zero = {0.f, 0.f, 0.f, 0.f};
  floatx4 acc[8][6];
#pragma unroll
  for (int i = 0; i < 8; ++i)
#pragma unroll
    for (int j = 0; j < 6; ++j) acc[i][j] = zero;

#define STAGE_A(k0, ss)                                                 \
  { gl_lds16(pA0 + (k0), Sm + (ss) + tid * 8);                          \
    gl_lds16(pA1 + (k0), Sm + (ss) + (tid + 512) * 8); }
#define STAGE_B(k0, ss)                                                 \
  { gl_lds16(pB0 + (k0), Sm + (ss) + 8192 + tid * 8);                   \
    gl_lds16(pB1 + (k0), Sm + (ss) + 8192 + (tid + 512) * 8);           \
    gl_lds16(pB2 + (k0), Sm + (ss) + 8192 + (tid + 1024) * 8); }

  const int NT = K >> 5;                  // 32
  STAGE_A(0, 0)      STAGE_B(0, 0)
  STAGE_A(32, 20480) STAGE_B(32, 20480)
  int sb = 0;
  int ss = 40960;

  for (int t = 0; t < NT; ++t) {
    if (t < NT - 1) asm volatile("s_waitcnt vmcnt(5)" ::: "memory");
    else            asm volatile("s_waitcnt vmcnt(0)" ::: "memory");
    __builtin_amdgcn_s_barrier();   // top barrier: tile t resident; orders slot reuse.

    const char* LB = (const char*)(Sm + sb);
    const int k2 = (t + 2) * 32;
    const bool st = (t + 2 < NT);

    // ---- phase 1: A0..A3 x B0..B5 ----
    bhalf8 a0 = *(const bhalf8*)(LB + ab0);
    bhalf8 a1 = *(const bhalf8*)(LB + ab0 + 1024);
    bhalf8 a2 = *(const bhalf8*)(LB + ab0 + 2048);
    bhalf8 a3 = *(const bhalf8*)(LB + ab0 + 3072);
    bhalf8 b0 = *(const bhalf8*)(LB + bb0);
    bhalf8 b1 = *(const bhalf8*)(LB + bb0 + 1024);
    bhalf8 b2 = *(const bhalf8*)(LB + bb0 + 2048);
    bhalf8 b3 = *(const bhalf8*)(LB + bb0 + 3072);
    bhalf8 b4 = *(const bhalf8*)(LB + bb0 + 4096);
    bhalf8 b5 = *(const bhalf8*)(LB + bb0 + 5120);
    if (st) STAGE_A(k2, ss)
    __builtin_amdgcn_s_setprio(1);
#define MROW(i, av)                                                              \
    acc[i][0] = __builtin_amdgcn_mfma_f32_16x16x32_bf16(av, b0, acc[i][0], 0, 0, 0); \
    acc[i][1] = __builtin_amdgcn_mfma_f32_16x16x32_bf16(av, b1, acc[i][1], 0, 0, 0); \
    acc[i][2] = __builtin_amdgcn_mfma_f32_16x16x32_bf16(av, b2, acc[i][2], 0, 0, 0); \
    acc[i][3] = __builtin_amdgcn_mfma_f32_16x16x32_bf16(av, b3, acc[i][3], 0, 0, 0); \
    acc[i][4] = __builtin_amdgcn_mfma_f32_16x16x32_bf16(av, b4, acc[i][4], 0, 0, 0); \
    acc[i][5] = __builtin_amdgcn_mfma_f32_16x16x32_bf16(av, b5, acc[i][5], 0, 0, 0);
    MROW(0, a0) MROW(1, a1) MROW(2, a2) MROW(3, a3)
    __builtin_amdgcn_s_setprio(0);
    __builtin_amdgcn_s_barrier();          // mid-tile lockstep

    // ---- phase 2: A4..A7 x B0..B5 ----
    bhalf8 a4 = *(const bhalf8*)(LB + ab0 + 4096);
    bhalf8 a5 = *(const bhalf8*)(LB + ab0 + 5120);
    bhalf8 a6 = *(const bhalf8*)(LB + ab0 + 6144);
    bhalf8 a7 = *(const bhalf8*)(LB + ab0 + 7168);
    if (st) STAGE_B(k2, ss)
    __builtin_amdgcn_s_setprio(1);
    MROW(4, a4) MROW(5, a5) MROW(6, a6) MROW(7, a7)
#undef MROW
    __builtin_amdgcn_s_setprio(0);
    // no end barrier: next iteration's top barrier orders slot reuse (ring-3).

    sb = (sb == 40960) ? 0 : sb + 20480;
    ss = (ss == 40960) ? 0 : ss + 20480;
  }
#undef STAGE_A
#undef STAGE_B

#pragma unroll
  for (int i = 0; i < 8; ++i) {
    int row = m0 + wm * 128 + i * 16 + (l4 << 2);
#pragma unroll
    for (int j = 0; j < 6; ++j) {
      int col = n0 + wn * 96 + j * 16 + l15;
      float bb = bias[col];
      if (!FUSEV || col < 2048) {
#pragma unroll
        for (int r = 0; r < 4; ++r)
          C[(size_t)(row + r) * N + col] = f2bf(acc[i][j][r] + bb);
      } else {
        // V section: scatter to per-head transposed Vt[(b*16+h)*64+dk][s]
        int vc = col - 2048;
        int h2 = vc >> 6, dk = vc & 63;
        int b2 = row >> 11, s = row & 2047;
        ushort4 pv;
        pv.x = f2bf(acc[i][j][0] + bb);
        pv.y = f2bf(acc[i][j][1] + bb);
        pv.z = f2bf(acc[i][j][2] + bb);
        pv.w = f2bf(acc[i][j][3] + bb);
        *(ushort4*)(Vt + ((size_t)((b2 * 16 + h2) * 64 + dk)) * SB + s) = pv;
      }
    }
  }
}

// ---------------- GEMM v6 (proj): C = A @ Bt^T + bias ----------------
// BM=256 BN=128 BK=32. 512 thr = 8 waves (4Mx2N, 64x64). Ring-3, 2 barriers/tile.
template <bool F32OUT>
__global__ __launch_bounds__(512, 4) void gemm_v6(
    const unsigned short* __restrict__ A,
    const unsigned short* __restrict__ Bt,
    const float* __restrict__ bias,
    void* __restrict__ Cv,
    int M, int N, int K) {
  __shared__ __align__(16) unsigned short Sm[3 * 12288];   // 73728 B
  const int tid = threadIdx.x;
  const int lane = tid & 63;
  const int w = tid >> 6;
  const int l15 = lane & 15, l4 = lane >> 4;
  const int wr = (w >> 1) * 64;
  const int wc = (w & 1) * 64;

  const int gx = gridDim.x;
  int lin = blockIdx.y * gx + blockIdx.x;
  const int cpx = (gx * gridDim.y) >> 3;
  lin = (lin & 7) * cpx + (lin >> 3);
  const int m0 = (lin / gx) * 256;
  const int n0 = (lin % gx) * 128;

  const int idx0 = tid, idx1 = tid + 512;
  const unsigned short* pA0 = A + (size_t)(m0 + (idx0 >> 2)) * K + (((idx0 & 3) ^ ((idx0 >> 3) & 3)) * 8);
  const unsigned short* pA1 = A + (size_t)(m0 + (idx1 >> 2)) * K + (((idx1 & 3) ^ ((idx1 >> 3) & 3)) * 8);
  const unsigned short* pB  = Bt + (size_t)(n0 + (tid >> 2)) * K + (((tid & 3) ^ ((tid >> 3) & 3)) * 8);

  int abyte[4], bbyte[4];
#pragma unroll
  for (int i = 0; i < 4; ++i) {
    int ra = wr + i * 16 + l15;
    abyte[i] = ra * 64 + ((l4 ^ ((ra >> 1) & 3)) << 4);
    int rb = wc + i * 16 + l15;
    bbyte[i] = 16384 + rb * 64 + ((l4 ^ ((rb >> 1) & 3)) << 4);
  }

  const floatx4 zero = {0.f, 0.f, 0.f, 0.f};
  floatx4 acc[4][4];
#pragma unroll
  for (int i = 0; i < 4; ++i)
#pragma unroll
    for (int j = 0; j < 4; ++j) acc[i][j] = zero;

#define STAGE_A6(k0, sbase)                                             \
  { gl_lds16(pA0 + (k0), Sm + (sbase) + idx0 * 8);                      \
    gl_lds16(pA1 + (k0), Sm + (sbase) + idx1 * 8); }
#define STAGE_B6(k0, sbase)                                             \
  { gl_lds16(pB + (k0), Sm + (sbase) + 8192 + tid * 8); }

  const int NT = K >> 5;
  STAGE_A6(0, 0)  STAGE_B6(0, 0)
  STAGE_A6(32, 12288) STAGE_B6(32, 12288)
  int sb = 0;
  int ss = 24576;

  for (int t = 0; t < NT; ++t) {
    if (t < NT - 1) asm volatile("s_waitcnt vmcnt(3)" ::: "memory");
    else            asm volatile("s_waitcnt vmcnt(0)" ::: "memory");
    __builtin_amdgcn_s_barrier();

    const char* LB = (const char*)(Sm + sb);
    const int k2 = (t + 2) * 32;
    const bool st = (t + 2 < NT);

    bhalf8 a0 = *(const bhalf8*)(LB + abyte[0]);
    bhalf8 a1 = *(const bhalf8*)(LB + abyte[1]);
    bhalf8 b0 = *(const bhalf8*)(LB + bbyte[0]);
    bhalf8 b1 = *(const bhalf8*)(LB + bbyte[1]);
    bhalf8 b2 = *(const bhalf8*)(LB + bbyte[2]);
    bhalf8 b3 = *(const bhalf8*)(LB + bbyte[3]);
    if (st) STAGE_A6(k2, ss)
    __builtin_amdgcn_s_setprio(1);
    acc[0][0] = __builtin_amdgcn_mfma_f32_16x16x32_bf16(a0, b0, acc[0][0], 0, 0, 0);
    acc[0][1] = __builtin_amdgcn_mfma_f32_16x16x32_bf16(a0, b1, acc[0][1], 0, 0, 0);
    acc[0][2] = __builtin_amdgcn_mfma_f32_16x16x32_bf16(a0, b2, acc[0][2], 0, 0, 0);
    acc[0][3] = __builtin_amdgcn_mfma_f32_16x16x32_bf16(a0, b3, acc[0][3], 0, 0, 0);
    acc[1][0] = __builtin_amdgcn_mfma_f32_16x16x32_bf16(a1, b0, acc[1][0], 0, 0, 0);
    acc[1][1] = __builtin_amdgcn_mfma_f32_16x16x32_bf16(a1, b1, acc[1][1], 0, 0, 0);
    acc[1][2] = __builtin_amdgcn_mfma_f32_16x16x32_bf16(a1, b2, acc[1][2], 0, 0, 0);
    acc[1][3] = __builtin_amdgcn_mfma_f32_16x16x32_bf16(a1, b3, acc[1][3], 0, 0, 0);
    __builtin_amdgcn_s_setprio(0);
    __builtin_amdgcn_s_barrier();          // mid-tile lockstep

    bhalf8 a2 = *(const bhalf8*)(LB + abyte[2]);
    bhalf8 a3 = *(const bhalf8*)(LB + abyte[3]);
    if (st) STAGE_B6(k2, ss)
    __builtin_amdgcn_s_setprio(1);
    acc[2][0] = __builtin_amdgcn_mfma_f32_16x16x32_bf16(a2, b0, acc[2][0], 0, 0, 0);
    acc[2][1] = __builtin_amdgcn_mfma_f32_16x16x32_bf16(a2, b1, acc[2][1], 0, 0, 0);
    acc[2][2] = __builtin_amdgcn_mfma_f32_16x16x32_bf16(a2, b2, acc[2][2], 0, 0, 0);
    acc[2][3] = __builtin_amdgcn_mfma_f32_16x16x32_bf16(a2, b3, acc[2][3], 0, 0, 0);
    acc[3][0] = __builtin_amdgcn_mfma_f32_16x16x32_bf16(a3, b0, acc[3][0], 0, 0, 0);
    acc[3][1] = __builtin_amdgcn_mfma_f32_16x16x32_bf16(a3, b1, acc[3][1], 0, 0, 0);
    acc[3][2] = __builtin_amdgcn_mfma_f32_16x16x32_bf16(a3, b2, acc[3][2], 0, 0, 0);
    acc[3][3] = __builtin_amdgcn_mfma_f32_16x16x32_bf16(a3, b3, acc[3][3], 0, 0, 0);
    __builtin_amdgcn_s_setprio(0);
    // no end barrier (ring-3 ordering via next top barrier)

    sb = (sb == 24576) ? 0 : sb + 12288;
    ss = (ss == 24576) ? 0 : ss + 12288;
  }
#undef STAGE_A6
#undef STAGE_B6

  float* Cf = (float*)Cv;
  unsigned short* Cb = (unsigned short*)Cv;
#pragma unroll
  for (int i = 0; i < 4; ++i) {
    int row = m0 + wr + i * 16 + (l4 << 2);
#pragma unroll
    for (int j = 0; j < 4; ++j) {
      int col = n0 + wc + j * 16 + l15;
      float bb = bias[col];
#pragma unroll
      for (int r = 0; r < 4; ++r) {
        float v = acc[i][j][r] + bb;
        size_t idx = (size_t)(row + r) * N + col;
        if constexpr (F32OUT) Cf[idx] = v;
        else Cb[idx] = f2bf(v);
      }
    }
  }
}

// ---------------- flash attention v4 (R10 config: launch_bounds(256,4)) ----------------
__global__ __launch_bounds__(256, 4) void flash_attn4(
    const unsigned short* __restrict__ qkv,   // [B*S][3H] bf16
    const unsigned short* __restrict__ Vt,    // [bh*64+dk][S] bf16
    unsigned short* __restrict__ outp) {      // [B*S][H]  bf16
  __shared__ __align__(16) unsigned short Sm[4 * 4096];

  const int tid = threadIdx.x;
  const int lane = tid & 63;
  const int w = tid >> 6;
  const int hi = lane >> 5;
  const int qc = lane & 31;
  const int bh = blockIdx.x;
  const int b = bh >> 4, h = bh & 15;
  const int qt = 15 - (int)blockIdx.y;   // big tiles dispatch first
  const int wq0 = qt * 128 + w * 32;
  const size_t rowbase = (size_t)b * SB;
  const int qg = wq0 + qc;
  const int nt = 2 * qt + 2;             // always even

  bhalf8 qf[4];
  {
    const unsigned short* qp = qkv + (rowbase + qg) * H3 + h * 64 + hi * 8;
#pragma unroll
    for (int kk = 0; kk < 4; ++kk) {
      bhalf8 v = *(const bhalf8*)(qp + kk * 16);
      bhalf8 o;
#pragma unroll
      for (int j = 0; j < 8; ++j)
        o[j] = (short)f2bf(bf2f((unsigned short)v[j]) * 0.18033688f);
      qf[kk] = o;
    }
  }

  const floatx16 Z16 = {0,0,0,0,0,0,0,0,0,0,0,0,0,0,0,0};
  floatx16 acc0 = Z16, acc1 = Z16;   // O^T: col q=qc, rows dk
  float l_half = 0.f;

  const char* LB = (const char*)Sm;
  int koff[8];
#pragma unroll
  for (int kk = 0; kk < 4; ++kk) {
    int xo = (((2 * kk + hi) ^ (qc & 7)) << 4);
    koff[2 * kk]     = qc * 128 + xo;
    koff[2 * kk + 1] = (32 + qc) * 128 + xo;
  }

  const int srow = tid >> 3, schk = tid & 7;
  const int sxe = (schk ^ (srow & 7)) * 8;
  const unsigned short* kp = qkv + (rowbase + srow) * H3 + HB + h * 64 + sxe;
  const unsigned short* vp = Vt + ((size_t)bh * 64 + srow) * SB + sxe;

  {
    unsigned short* kb = Sm + tid * 8;
    gl_lds16(kp, kb);
    gl_lds16(kp + 32 * H3, kb + 2048);
    gl_lds16(vp, kb + 8192);
    gl_lds16(vp + 32 * SB, kb + 8192 + 2048);
  }

#define QKK(BUFB, kk)                                                              \
      { bhalf8 ka = *(const bhalf8*)(LB + (BUFB) + koff[2*(kk)]);                  \
        s0 = __builtin_amdgcn_mfma_f32_32x32x16_bf16(ka, qf[kk], s0, 0, 0, 0);     \
        bhalf8 kb2 = *(const bhalf8*)(LB + (BUFB) + koff[2*(kk)+1]);               \
        s1 = __builtin_amdgcn_mfma_f32_32x32x16_bf16(kb2, qf[kk], s1, 0, 0, 0); }
#define PVC(BUFB, c, pfv)                                                          \
      { bhalf8 va = *(const bhalf8*)(LB + 16384 + (BUFB) + koff[2*(c)]);           \
        acc0 = __builtin_amdgcn_mfma_f32_32x32x16_bf16(va, pfv, acc0, 0, 0, 0);    \
        bhalf8 vb2 = *(const bhalf8*)(LB + 16384 + (BUFB) + koff[2*(c)+1]);        \
        acc1 = __builtin_amdgcn_mfma_f32_32x32x16_bf16(vb2, pfv, acc1, 0, 0, 0); }
#define MSK0(r) { if (k0 + (((r)&3) + 8*((r)>>2)) + 4*hi > qg)      s0[r] = -3.0e38f; }
#define MSK1(r) { if (k0 + 32 + (((r)&3) + 8*((r)>>2)) + 4*hi > qg) s1[r] = -3.0e38f; }
#define PEXP(r) { s0[r] = EXP2(s0[r]); s1[r] = EXP2(s1[r]); rsx[(r)&3] += s0[r] + s1[r]; }
  union PW { int i[4]; bhalf8 v; };
#define PACK2(dst, sv, rb)                                               \
      { int A0 = pkbf(sv[rb + 0], sv[rb + 1]);                           \
        int A1 = pkbf(sv[rb + 2], sv[rb + 3]);                           \
        int B0 = pkbf(sv[rb + 4], sv[rb + 5]);                           \
        int B1 = pkbf(sv[rb + 6], sv[rb + 7]);                           \
        auto r0 = __builtin_amdgcn_permlane32_swap(A0, B0, false, false);\
        auto r1 = __builtin_amdgcn_permlane32_swap(A1, B1, false, false);\
        PW u;                                                            \
        u.i[0] = r0[0]; u.i[1] = r1[0];                                  \
        u.i[2] = r0[1]; u.i[3] = r1[1];                                  \
        dst = u.v; }

#define FLASH_COMPUTE(BUFB)                                                        \
    { floatx16 s0 = Z16, s1 = Z16;                                                 \
      __builtin_amdgcn_s_setprio(1);                                               \
      QKK(BUFB, 0) QKK(BUFB, 1) QKK(BUFB, 2) QKK(BUFB, 3)                          \
      __builtin_amdgcn_s_setprio(0);                                               \
      if (k0 + 63 > wq0) { REP16(MSK0) REP16(MSK1) }                               \
      float rsx[4] = {0.f, 0.f, 0.f, 0.f};                                         \
      REP16(PEXP)                                                                  \
      l_half += (rsx[0] + rsx[1]) + (rsx[2] + rsx[3]);                             \
      bhalf8 pf0, pf1, pf2, pf3;                                                   \
      PACK2(pf0, s0, 0) PACK2(pf1, s0, 8) PACK2(pf2, s1, 0) PACK2(pf3, s1, 8)      \
      __builtin_amdgcn_s_setprio(1);                                               \
      PVC(BUFB, 0, pf0) PVC(BUFB, 1, pf1) PVC(BUFB, 2, pf2) PVC(BUFB, 3, pf3)      \
      __builtin_amdgcn_s_setprio(0); }

#define DO_STEP(T, BUF)                                                            \
  { __syncthreads();                                                               \
    if ((T) + 1 < nt) {                                                            \
      kp += 64 * H3; vp += 64;                                                     \
      unsigned short* kb = Sm + (1 - (BUF)) * 4096 + tid * 8;                      \
      gl_lds16(kp, kb); gl_lds16(kp + 32 * H3, kb + 2048);                         \
      gl_lds16(vp, kb + 8192); gl_lds16(vp + 32 * SB, kb + 8192 + 2048);           \
    }                                                                              \
    const int k0 = (T) * 64;                                                       \
    if (k0 <= wq0 + 31) FLASH_COMPUTE((BUF) * 8192)                                \
  }

  for (int t = 0; t < nt; t += 2) {
    DO_STEP(t, 0)
    DO_STEP(t + 1, 1)
  }

  const float l_full = l_half + __shfl_xor(l_half, 32);
  const float inv_l = 1.f / l_full;
  unsigned short* op = outp + (rowbase + qg) * HB + h * 64;
#pragma unroll
  for (int tq = 0; tq < 4; ++tq) {
    ushort4 st;
    st.x = f2bf(acc0[4 * tq + 0] * inv_l);
    st.y = f2bf(acc0[4 * tq + 1] * inv_l);
    st.z = f2bf(acc0[4 * tq + 2] * inv_l);
    st.w = f2bf(acc0[4 * tq + 3] * inv_l);
    *(ushort4*)(op + 8 * tq + 4 * hi) = st;
    ushort4 su;
    su.x = f2bf(acc1[4 * tq + 0] * inv_l);
    su.y = f2bf(acc1[4 * tq + 1] * inv_l);
    su.z = f2bf(acc1[4 * tq + 2] * inv_l);
    su.w = f2bf(acc1[4 * tq + 3] * inv_l);
    *(ushort4*)(op + 32 + 8 * tq + 4 * hi) = su;
  }
}

extern "C" void kernel_launch(void* const* d_in, const int* in_sizes, int n_in,
                              void* d_out, int out_size, void* d_ws, size_t ws_size,
                              hipStream_t stream) {
  const float* x      = (const float*)d_in[0];   // [4,2048,1024]
  const float* W_attn = (const float*)d_in[1];   // [1024,3072]
  const float* b_attn = (const float*)d_in[2];   // [3072]
  const float* W_proj = (const float*)d_in[3];   // [1024,1024]
  const float* b_proj = (const float*)d_in[4];   // [1024]
  float* out = (float*)d_out;                    // [4,2048,1024] f32

  char* ws = (char*)d_ws;
  unsigned short* x_bf    = (unsigned short*)(ws);                 // 16777216 B
  unsigned short* Wt_attn = (unsigned short*)(ws + 16777216);      //  6291456 B
  unsigned short* Wt_proj = (unsigned short*)(ws + 23068672);      //  2097152 B
  unsigned short* qkv     = (unsigned short*)(ws + 25165824);      // 50331648 B
  unsigned short* attn    = (unsigned short*)(ws + 75497472);      // 16777216 B
  // Fused path: Vt gets its own region (x_bf is LIVE during the qkv GEMM).
  // Fallback: Vt aliases x_bf and uses the transpose_v kernel.
  const bool fuse = ws_size >= (size_t)92274688 + 16777216;
  unsigned short* VtF = (unsigned short*)(ws + 92274688);
  unsigned short* Vt  = fuse ? VtF : x_bf;

  // fused prep: cvt(x) + W_attn^T + W_proj^T in one launch
  prep_all<<<12288, 256, 0, stream>>>(x, x_bf, W_attn, Wt_attn, W_proj, Wt_proj);

  // qkv = x @ W_attn + b_attn (bf16 out) — grid 8x32 = 256 = 1/CU exact
  if (fuse) {
    gemm_v9<true><<<dim3(8, 32), 512, 0, stream>>>(x_bf, Wt_attn, b_attn, qkv, VtF,
                                                   8192, 3072, 1024);
  } else {
    gemm_v9<false><<<dim3(8, 32), 512, 0, stream>>>(x_bf, Wt_attn, b_attn, qkv, nullptr,
                                                    8192, 3072, 1024);
    transpose_v<<<dim3(64, 2, 64), dim3(32, 8), 0, stream>>>(qkv, Vt);
  }
  // flash attention -> attn[8192][1024] (merged heads)
  flash_attn4<<<dim3(64, 16), 256, 0, stream>>>(qkv, Vt, attn);
  // out = attn @ W_proj + b_proj (f32 out) — grid 8x32 = 256 (%8==0)
  gemm_v6<true><<<dim3(8, 32), 512, 0, stream>>>(attn, Wt_proj, b_proj, out,
                                                 8192, 1024, 1024);
}

// Round 18
// 141.209 us; speedup vs baseline: 1.1914x; 1.0023x over previous
//
#include <hip/hip_runtime.h>
#include <hip/hip_bf16.h>

// Fused causal MHA block for MI355X (gfx950).
// B=4 S=2048 H=1024 NH=16 DK=64. Inputs f32; compute in bf16 MFMA (f32 accum).
// Pipeline: prep_all (fused cvt(x)+W^T) | GEMM qkv (2-barrier ring-3, scatter
// FUSEV) | flash v4 (256,4) | GEMM proj. R17: removed s_setprio from the
// lockstep GEMMs (m190: setprio measured negative on barrier-locked GEMM;
// positive only with wave role-split). Flash keeps setprio (m191 regime).

typedef __attribute__((ext_vector_type(8))) short bhalf8;    // 8 bf16 = 4 VGPRs
typedef __attribute__((ext_vector_type(4))) float floatx4;   // MFMA 16x16 accum
typedef __attribute__((ext_vector_type(16))) float floatx16; // MFMA 32x32 accum

#define SB 2048
#define HB 1024
#define H3 3072

#if __has_builtin(__builtin_amdgcn_exp2f)
#define EXP2(x) __builtin_amdgcn_exp2f(x)
#else
#define EXP2(x) exp2f(x)
#endif

__device__ __forceinline__ float bf2f(unsigned short u) {
  union { unsigned int i; float f; } c; c.i = ((unsigned int)u) << 16; return c.f;
}
__device__ __forceinline__ unsigned short f2bf(float f) {
  union { float f; unsigned int i; } c; c.f = f;
  unsigned int r = c.i + 0x7fffu + ((c.i >> 16) & 1u);   // RNE
  return (unsigned short)(r >> 16);
}
__device__ __forceinline__ int pkbf(float lo, float hi_) {
  union { __hip_bfloat162 h; int i; } u;
  u.h = __float22bfloat162_rn(make_float2(lo, hi_));  // lo -> bits 0..15
  return u.i;
}

// async global->LDS, 16B per lane (dest must be uniform-base + lane*16).
__device__ __forceinline__ void gl_lds16(const unsigned short* g, unsigned short* l) {
  __builtin_amdgcn_global_load_lds(
      (const __attribute__((address_space(1))) unsigned int*)g,
      (__attribute__((address_space(3))) unsigned int*)l, 16, 0, 0);
}

#define REP16(OP) OP(0) OP(1) OP(2) OP(3) OP(4) OP(5) OP(6) OP(7) \
                  OP(8) OP(9) OP(10) OP(11) OP(12) OP(13) OP(14) OP(15)

// ---------------- fused prep: cvt(x) | W_attn^T | W_proj^T ----------------
__global__ __launch_bounds__(256) void prep_all(
    const float* __restrict__ x, unsigned short* __restrict__ x_bf,
    const float* __restrict__ Wa, unsigned short* __restrict__ Wat,
    const float* __restrict__ Wp, unsigned short* __restrict__ Wpt) {
  const int bid = blockIdx.x;
  if (bid < 8192) {
    int i = (bid * 256 + threadIdx.x) * 4;
    float4 v = *(const float4*)(x + i);
    ushort4 o;
    o.x = f2bf(v.x); o.y = f2bf(v.y); o.z = f2bf(v.z); o.w = f2bf(v.w);
    *(ushort4*)(x_bf + i) = o;
    return;
  }
  __shared__ float tile[32][33];
  const float* in;
  unsigned short* out;
  int K = 1024, N, n0, k0;
  if (bid < 11264) {
    int tb = bid - 8192;              // 96 x 32 tiles
    N = 3072; in = Wa; out = Wat;
    n0 = (tb % 96) * 32; k0 = (tb / 96) * 32;
  } else {
    int tb = bid - 11264;             // 32 x 32 tiles
    N = 1024; in = Wp; out = Wpt;
    n0 = (tb % 32) * 32; k0 = (tb / 32) * 32;
  }
  const int tx = threadIdx.x & 31, ty = threadIdx.x >> 5;
  for (int i = ty; i < 32; i += 8)
    tile[i][tx] = in[(size_t)(k0 + i) * N + n0 + tx];
  __syncthreads();
  for (int i = ty; i < 32; i += 8)
    out[(size_t)(n0 + i) * K + k0 + tx] = f2bf(tile[tx][i]);
}

// ---------------- V part of qkv -> Vt[bh*64+dk][S] (fallback path only) ----------------
__global__ void transpose_v(const unsigned short* __restrict__ qkv,
                            unsigned short* __restrict__ Vt) {
  __shared__ unsigned short tile[32][33];
  const int bh = blockIdx.z;
  const int b = bh >> 4, h = bh & 15;
  const int s0 = blockIdx.x * 32;
  const int d0 = blockIdx.y * 32;
  const int tx = threadIdx.x;
  const unsigned short* src = qkv + (size_t)(b * SB + s0) * H3 + 2 * HB + h * 64 + d0;
  for (int i = threadIdx.y; i < 32; i += 8)
    tile[i][tx] = src[(size_t)i * H3 + tx];
  __syncthreads();
  unsigned short* dst = Vt + ((size_t)bh * 64 + d0) * SB + s0;
  for (int i = threadIdx.y; i < 32; i += 8)
    dst[(size_t)i * SB + tx] = tile[tx][i];
}

// ---------------- GEMM (qkv): C[M=8192][N=3072] = A @ Bt^T + bias, bf16 out ----
// BM=256 BN=384 BK=32. 512 thr = 8 waves (2Mx4N), wave tile 128x96 (acc 8x6).
// Ring-3 slots of 40KB; 5 gl_lds16/thread/tile staged 2 ahead; vmcnt(5) at tile
// top; 2 barriers/tile; no setprio (lockstep GEMM regime, m190).
template <bool FUSEV>
__global__ __launch_bounds__(512, 2) void gemm_v9(
    const unsigned short* __restrict__ A,
    const unsigned short* __restrict__ Bt,
    const float* __restrict__ bias,
    unsigned short* __restrict__ C,
    unsigned short* __restrict__ Vt,
    int M, int N, int K) {
  __shared__ __align__(16) unsigned short Sm[3 * 20480];   // 122880 B
  const int tid = threadIdx.x;
  const int lane = tid & 63;
  const int w = tid >> 6;
  const int l15 = lane & 15, l4 = lane >> 4;
  const int wm = w >> 2, wn = w & 3;

  // bijective XCD swizzle (grid = 256, %8==0)
  const int gx = gridDim.x;               // 8
  int lin = blockIdx.y * gx + blockIdx.x;
  const int cpx = (gx * gridDim.y) >> 3;
  lin = (lin & 7) * cpx + (lin >> 3);
  const int m0 = (lin / gx) * 256;
  const int n0 = (lin % gx) * 384;

  const int rb0 = tid >> 2;
  const int co = (((tid & 3) ^ ((tid >> 3) & 3)) * 8);
  const unsigned short* pA0 = A + (size_t)(m0 + rb0) * K + co;
  const unsigned short* pA1 = pA0 + (size_t)128 * K;
  const unsigned short* pB0 = Bt + (size_t)(n0 + rb0) * K + co;
  const unsigned short* pB1 = pB0 + (size_t)128 * K;
  const unsigned short* pB2 = pB0 + (size_t)256 * K;

  const int ra0 = wm * 128 + l15;
  const int ab0 = ra0 * 64 + ((l4 ^ ((ra0 >> 1) & 3)) << 4);
  const int rbq = wn * 96 + l15;
  const int bb0 = 16384 + rbq * 64 + ((l4 ^ ((rbq >> 1) & 3)) << 4);

  const floatx4 zero = {0.f, 0.f, 0.f, 0.f};
  floatx4 acc[8][6];
#pragma unroll
  for (int i = 0; i < 8; ++i)
#pragma unroll
    for (int j = 0; j < 6; ++j) acc[i][j] = zero;

#define STAGE_A(k0, ss)                                                 \
  { gl_lds16(pA0 + (k0), Sm + (ss) + tid * 8);                          \
    gl_lds16(pA1 + (k0), Sm + (ss) + (tid + 512) * 8); }
#define STAGE_B(k0, ss)                                                 \
  { gl_lds16(pB0 + (k0), Sm + (ss) + 8192 + tid * 8);                   \
    gl_lds16(pB1 + (k0), Sm + (ss) + 8192 + (tid + 512) * 8);           \
    gl_lds16(pB2 + (k0), Sm + (ss) + 8192 + (tid + 1024) * 8); }

  const int NT = K >> 5;                  // 32
  STAGE_A(0, 0)      STAGE_B(0, 0)
  STAGE_A(32, 20480) STAGE_B(32, 20480)
  int sb = 0;
  int ss = 40960;

  for (int t = 0; t < NT; ++t) {
    if (t < NT - 1) asm volatile("s_waitcnt vmcnt(5)" ::: "memory");
    else            asm volatile("s_waitcnt vmcnt(0)" ::: "memory");
    __builtin_amdgcn_s_barrier();   // top barrier: tile t resident; orders slot reuse.

    const char* LB = (const char*)(Sm + sb);
    const int k2 = (t + 2) * 32;
    const bool st = (t + 2 < NT);

    // ---- phase 1: A0..A3 x B0..B5 ----
    bhalf8 a0 = *(const bhalf8*)(LB + ab0);
    bhalf8 a1 = *(const bhalf8*)(LB + ab0 + 1024);
    bhalf8 a2 = *(const bhalf8*)(LB + ab0 + 2048);
    bhalf8 a3 = *(const bhalf8*)(LB + ab0 + 3072);
    bhalf8 b0 = *(const bhalf8*)(LB + bb0);
    bhalf8 b1 = *(const bhalf8*)(LB + bb0 + 1024);
    bhalf8 b2 = *(const bhalf8*)(LB + bb0 + 2048);
    bhalf8 b3 = *(const bhalf8*)(LB + bb0 + 3072);
    bhalf8 b4 = *(const bhalf8*)(LB + bb0 + 4096);
    bhalf8 b5 = *(const bhalf8*)(LB + bb0 + 5120);
    if (st) STAGE_A(k2, ss)
#define MROW(i, av)                                                              \
    acc[i][0] = __builtin_amdgcn_mfma_f32_16x16x32_bf16(av, b0, acc[i][0], 0, 0, 0); \
    acc[i][1] = __builtin_amdgcn_mfma_f32_16x16x32_bf16(av, b1, acc[i][1], 0, 0, 0); \
    acc[i][2] = __builtin_amdgcn_mfma_f32_16x16x32_bf16(av, b2, acc[i][2], 0, 0, 0); \
    acc[i][3] = __builtin_amdgcn_mfma_f32_16x16x32_bf16(av, b3, acc[i][3], 0, 0, 0); \
    acc[i][4] = __builtin_amdgcn_mfma_f32_16x16x32_bf16(av, b4, acc[i][4], 0, 0, 0); \
    acc[i][5] = __builtin_amdgcn_mfma_f32_16x16x32_bf16(av, b5, acc[i][5], 0, 0, 0);
    MROW(0, a0) MROW(1, a1) MROW(2, a2) MROW(3, a3)
    __builtin_amdgcn_s_barrier();          // mid-tile lockstep

    // ---- phase 2: A4..A7 x B0..B5 ----
    bhalf8 a4 = *(const bhalf8*)(LB + ab0 + 4096);
    bhalf8 a5 = *(const bhalf8*)(LB + ab0 + 5120);
    bhalf8 a6 = *(const bhalf8*)(LB + ab0 + 6144);
    bhalf8 a7 = *(const bhalf8*)(LB + ab0 + 7168);
    if (st) STAGE_B(k2, ss)
    MROW(4, a4) MROW(5, a5) MROW(6, a6) MROW(7, a7)
#undef MROW
    // no end barrier: next iteration's top barrier orders slot reuse (ring-3).

    sb = (sb == 40960) ? 0 : sb + 20480;
    ss = (ss == 40960) ? 0 : ss + 20480;
  }
#undef STAGE_A
#undef STAGE_B

#pragma unroll
  for (int i = 0; i < 8; ++i) {
    int row = m0 + wm * 128 + i * 16 + (l4 << 2);
#pragma unroll
    for (int j = 0; j < 6; ++j) {
      int col = n0 + wn * 96 + j * 16 + l15;
      float bb = bias[col];
      if (!FUSEV || col < 2048) {
#pragma unroll
        for (int r = 0; r < 4; ++r)
          C[(size_t)(row + r) * N + col] = f2bf(acc[i][j][r] + bb);
      } else {
        // V section: scatter to per-head transposed Vt[(b*16+h)*64+dk][s]
        int vc = col - 2048;
        int h2 = vc >> 6, dk = vc & 63;
        int b2 = row >> 11, s = row & 2047;
        ushort4 pv;
        pv.x = f2bf(acc[i][j][0] + bb);
        pv.y = f2bf(acc[i][j][1] + bb);
        pv.z = f2bf(acc[i][j][2] + bb);
        pv.w = f2bf(acc[i][j][3] + bb);
        *(ushort4*)(Vt + ((size_t)((b2 * 16 + h2) * 64 + dk)) * SB + s) = pv;
      }
    }
  }
}

// ---------------- GEMM v6 (proj): C = A @ Bt^T + bias ----------------
// BM=256 BN=128 BK=32. 512 thr = 8 waves (4Mx2N, 64x64). Ring-3, 2 barriers/tile,
// no setprio (lockstep GEMM regime).
template <bool F32OUT>
__global__ __launch_bounds__(512, 4) void gemm_v6(
    const unsigned short* __restrict__ A,
    const unsigned short* __restrict__ Bt,
    const float* __restrict__ bias,
    void* __restrict__ Cv,
    int M, int N, int K) {
  __shared__ __align__(16) unsigned short Sm[3 * 12288];   // 73728 B
  const int tid = threadIdx.x;
  const int lane = tid & 63;
  const int w = tid >> 6;
  const int l15 = lane & 15, l4 = lane >> 4;
  const int wr = (w >> 1) * 64;
  const int wc = (w & 1) * 64;

  const int gx = gridDim.x;
  int lin = blockIdx.y * gx + blockIdx.x;
  const int cpx = (gx * gridDim.y) >> 3;
  lin = (lin & 7) * cpx + (lin >> 3);
  const int m0 = (lin / gx) * 256;
  const int n0 = (lin % gx) * 128;

  const int idx0 = tid, idx1 = tid + 512;
  const unsigned short* pA0 = A + (size_t)(m0 + (idx0 >> 2)) * K + (((idx0 & 3) ^ ((idx0 >> 3) & 3)) * 8);
  const unsigned short* pA1 = A + (size_t)(m0 + (idx1 >> 2)) * K + (((idx1 & 3) ^ ((idx1 >> 3) & 3)) * 8);
  const unsigned short* pB  = Bt + (size_t)(n0 + (tid >> 2)) * K + (((tid & 3) ^ ((tid >> 3) & 3)) * 8);

  int abyte[4], bbyte[4];
#pragma unroll
  for (int i = 0; i < 4; ++i) {
    int ra = wr + i * 16 + l15;
    abyte[i] = ra * 64 + ((l4 ^ ((ra >> 1) & 3)) << 4);
    int rb = wc + i * 16 + l15;
    bbyte[i] = 16384 + rb * 64 + ((l4 ^ ((rb >> 1) & 3)) << 4);
  }

  const floatx4 zero = {0.f, 0.f, 0.f, 0.f};
  floatx4 acc[4][4];
#pragma unroll
  for (int i = 0; i < 4; ++i)
#pragma unroll
    for (int j = 0; j < 4; ++j) acc[i][j] = zero;

#define STAGE_A6(k0, sbase)                                             \
  { gl_lds16(pA0 + (k0), Sm + (sbase) + idx0 * 8);                      \
    gl_lds16(pA1 + (k0), Sm + (sbase) + idx1 * 8); }
#define STAGE_B6(k0, sbase)                                             \
  { gl_lds16(pB + (k0), Sm + (sbase) + 8192 + tid * 8); }

  const int NT = K >> 5;
  STAGE_A6(0, 0)  STAGE_B6(0, 0)
  STAGE_A6(32, 12288) STAGE_B6(32, 12288)
  int sb = 0;
  int ss = 24576;

  for (int t = 0; t < NT; ++t) {
    if (t < NT - 1) asm volatile("s_waitcnt vmcnt(3)" ::: "memory");
    else            asm volatile("s_waitcnt vmcnt(0)" ::: "memory");
    __builtin_amdgcn_s_barrier();

    const char* LB = (const char*)(Sm + sb);
    const int k2 = (t + 2) * 32;
    const bool st = (t + 2 < NT);

    bhalf8 a0 = *(const bhalf8*)(LB + abyte[0]);
    bhalf8 a1 = *(const bhalf8*)(LB + abyte[1]);
    bhalf8 b0 = *(const bhalf8*)(LB + bbyte[0]);
    bhalf8 b1 = *(const bhalf8*)(LB + bbyte[1]);
    bhalf8 b2 = *(const bhalf8*)(LB + bbyte[2]);
    bhalf8 b3 = *(const bhalf8*)(LB + bbyte[3]);
    if (st) STAGE_A6(k2, ss)
    acc[0][0] = __builtin_amdgcn_mfma_f32_16x16x32_bf16(a0, b0, acc[0][0], 0, 0, 0);
    acc[0][1] = __builtin_amdgcn_mfma_f32_16x16x32_bf16(a0, b1, acc[0][1], 0, 0, 0);
    acc[0][2] = __builtin_amdgcn_mfma_f32_16x16x32_bf16(a0, b2, acc[0][2], 0, 0, 0);
    acc[0][3] = __builtin_amdgcn_mfma_f32_16x16x32_bf16(a0, b3, acc[0][3], 0, 0, 0);
    acc[1][0] = __builtin_amdgcn_mfma_f32_16x16x32_bf16(a1, b0, acc[1][0], 0, 0, 0);
    acc[1][1] = __builtin_amdgcn_mfma_f32_16x16x32_bf16(a1, b1, acc[1][1], 0, 0, 0);
    acc[1][2] = __builtin_amdgcn_mfma_f32_16x16x32_bf16(a1, b2, acc[1][2], 0, 0, 0);
    acc[1][3] = __builtin_amdgcn_mfma_f32_16x16x32_bf16(a1, b3, acc[1][3], 0, 0, 0);
    __builtin_amdgcn_s_barrier();          // mid-tile lockstep

    bhalf8 a2 = *(const bhalf8*)(LB + abyte[2]);
    bhalf8 a3 = *(const bhalf8*)(LB + abyte[3]);
    if (st) STAGE_B6(k2, ss)
    acc[2][0] = __builtin_amdgcn_mfma_f32_16x16x32_bf16(a2, b0, acc[2][0], 0, 0, 0);
    acc[2][1] = __builtin_amdgcn_mfma_f32_16x16x32_bf16(a2, b1, acc[2][1], 0, 0, 0);
    acc[2][2] = __builtin_amdgcn_mfma_f32_16x16x32_bf16(a2, b2, acc[2][2], 0, 0, 0);
    acc[2][3] = __builtin_amdgcn_mfma_f32_16x16x32_bf16(a2, b3, acc[2][3], 0, 0, 0);
    acc[3][0] = __builtin_amdgcn_mfma_f32_16x16x32_bf16(a3, b0, acc[3][0], 0, 0, 0);
    acc[3][1] = __builtin_amdgcn_mfma_f32_16x16x32_bf16(a3, b1, acc[3][1], 0, 0, 0);
    acc[3][2] = __builtin_amdgcn_mfma_f32_16x16x32_bf16(a3, b2, acc[3][2], 0, 0, 0);
    acc[3][3] = __builtin_amdgcn_mfma_f32_16x16x32_bf16(a3, b3, acc[3][3], 0, 0, 0);
    // no end barrier (ring-3 ordering via next top barrier)

    sb = (sb == 24576) ? 0 : sb + 12288;
    ss = (ss == 24576) ? 0 : ss + 12288;
  }
#undef STAGE_A6
#undef STAGE_B6

  float* Cf = (float*)Cv;
  unsigned short* Cb = (unsigned short*)Cv;
#pragma unroll
  for (int i = 0; i < 4; ++i) {
    int row = m0 + wr + i * 16 + (l4 << 2);
#pragma unroll
    for (int j = 0; j < 4; ++j) {
      int col = n0 + wc + j * 16 + l15;
      float bb = bias[col];
#pragma unroll
      for (int r = 0; r < 4; ++r) {
        float v = acc[i][j][r] + bb;
        size_t idx = (size_t)(row + r) * N + col;
        if constexpr (F32OUT) Cf[idx] = v;
        else Cb[idx] = f2bf(v);
      }
    }
  }
}

// ---------------- flash attention v4 (keeps setprio; launch_bounds(256,4)) ----------------
__global__ __launch_bounds__(256, 4) void flash_attn4(
    const unsigned short* __restrict__ qkv,   // [B*S][3H] bf16
    const unsigned short* __restrict__ Vt,    // [bh*64+dk][S] bf16
    unsigned short* __restrict__ outp) {      // [B*S][H]  bf16
  __shared__ __align__(16) unsigned short Sm[4 * 4096];

  const int tid = threadIdx.x;
  const int lane = tid & 63;
  const int w = tid >> 6;
  const int hi = lane >> 5;
  const int qc = lane & 31;
  const int bh = blockIdx.x;
  const int b = bh >> 4, h = bh & 15;
  const int qt = 15 - (int)blockIdx.y;   // big tiles dispatch first
  const int wq0 = qt * 128 + w * 32;
  const size_t rowbase = (size_t)b * SB;
  const int qg = wq0 + qc;
  const int nt = 2 * qt + 2;             // always even

  bhalf8 qf[4];
  {
    const unsigned short* qp = qkv + (rowbase + qg) * H3 + h * 64 + hi * 8;
#pragma unroll
    for (int kk = 0; kk < 4; ++kk) {
      bhalf8 v = *(const bhalf8*)(qp + kk * 16);
      bhalf8 o;
#pragma unroll
      for (int j = 0; j < 8; ++j)
        o[j] = (short)f2bf(bf2f((unsigned short)v[j]) * 0.18033688f);
      qf[kk] = o;
    }
  }

  const floatx16 Z16 = {0,0,0,0,0,0,0,0,0,0,0,0,0,0,0,0};
  floatx16 acc0 = Z16, acc1 = Z16;   // O^T: col q=qc, rows dk
  float l_half = 0.f;

  const char* LB = (const char*)Sm;
  int koff[8];
#pragma unroll
  for (int kk = 0; kk < 4; ++kk) {
    int xo = (((2 * kk + hi) ^ (qc & 7)) << 4);
    koff[2 * kk]     = qc * 128 + xo;
    koff[2 * kk + 1] = (32 + qc) * 128 + xo;
  }

  const int srow = tid >> 3, schk = tid & 7;
  const int sxe = (schk ^ (srow & 7)) * 8;
  const unsigned short* kp = qkv + (rowbase + srow) * H3 + HB + h * 64 + sxe;
  const unsigned short* vp = Vt + ((size_t)bh * 64 + srow) * SB + sxe;

  {
    unsigned short* kb = Sm + tid * 8;
    gl_lds16(kp, kb);
    gl_lds16(kp + 32 * H3, kb + 2048);
    gl_lds16(vp, kb + 8192);
    gl_lds16(vp + 32 * SB, kb + 8192 + 2048);
  }

#define QKK(BUFB, kk)                                                              \
      { bhalf8 ka = *(const bhalf8*)(LB + (BUFB) + koff[2*(kk)]);                  \
        s0 = __builtin_amdgcn_mfma_f32_32x32x16_bf16(ka, qf[kk], s0, 0, 0, 0);     \
        bhalf8 kb2 = *(const bhalf8*)(LB + (BUFB) + koff[2*(kk)+1]);               \
        s1 = __builtin_amdgcn_mfma_f32_32x32x16_bf16(kb2, qf[kk], s1, 0, 0, 0); }
#define PVC(BUFB, c, pfv)                                                          \
      { bhalf8 va = *(const bhalf8*)(LB + 16384 + (BUFB) + koff[2*(c)]);           \
        acc0 = __builtin_amdgcn_mfma_f32_32x32x16_bf16(va, pfv, acc0, 0, 0, 0);    \
        bhalf8 vb2 = *(const bhalf8*)(LB + 16384 + (BUFB) + koff[2*(c)+1]);        \
        acc1 = __builtin_amdgcn_mfma_f32_32x32x16_bf16(vb2, pfv, acc1, 0, 0, 0); }
#define MSK0(r) { if (k0 + (((r)&3) + 8*((r)>>2)) + 4*hi > qg)      s0[r] = -3.0e38f; }
#define MSK1(r) { if (k0 + 32 + (((r)&3) + 8*((r)>>2)) + 4*hi > qg) s1[r] = -3.0e38f; }
#define PEXP(r) { s0[r] = EXP2(s0[r]); s1[r] = EXP2(s1[r]); rsx[(r)&3] += s0[r] + s1[r]; }
  union PW { int i[4]; bhalf8 v; };
#define PACK2(dst, sv, rb)                                               \
      { int A0 = pkbf(sv[rb + 0], sv[rb + 1]);                           \
        int A1 = pkbf(sv[rb + 2], sv[rb + 3]);                           \
        int B0 = pkbf(sv[rb + 4], sv[rb + 5]);                           \
        int B1 = pkbf(sv[rb + 6], sv[rb + 7]);                           \
        auto r0 = __builtin_amdgcn_permlane32_swap(A0, B0, false, false);\
        auto r1 = __builtin_amdgcn_permlane32_swap(A1, B1, false, false);\
        PW u;                                                            \
        u.i[0] = r0[0]; u.i[1] = r1[0];                                  \
        u.i[2] = r0[1]; u.i[3] = r1[1];                                  \
        dst = u.v; }

#define FLASH_COMPUTE(BUFB)                                                        \
    { floatx16 s0 = Z16, s1 = Z16;                                                 \
      __builtin_amdgcn_s_setprio(1);                                               \
      QKK(BUFB, 0) QKK(BUFB, 1) QKK(BUFB, 2) QKK(BUFB, 3)                          \
      __builtin_amdgcn_s_setprio(0);                                               \
      if (k0 + 63 > wq0) { REP16(MSK0) REP16(MSK1) }                               \
      float rsx[4] = {0.f, 0.f, 0.f, 0.f};                                         \
      REP16(PEXP)                                                                  \
      l_half += (rsx[0] + rsx[1]) + (rsx[2] + rsx[3]);                             \
      bhalf8 pf0, pf1, pf2, pf3;                                                   \
      PACK2(pf0, s0, 0) PACK2(pf1, s0, 8) PACK2(pf2, s1, 0) PACK2(pf3, s1, 8)      \
      __builtin_amdgcn_s_setprio(1);                                               \
      PVC(BUFB, 0, pf0) PVC(BUFB, 1, pf1) PVC(BUFB, 2, pf2) PVC(BUFB, 3, pf3)      \
      __builtin_amdgcn_s_setprio(0); }

#define DO_STEP(T, BUF)                                                            \
  { __syncthreads();                                                               \
    if ((T) + 1 < nt) {                                                            \
      kp += 64 * H3; vp += 64;                                                     \
      unsigned short* kb = Sm + (1 - (BUF)) * 4096 + tid * 8;                      \
      gl_lds16(kp, kb); gl_lds16(kp + 32 * H3, kb + 2048);                         \
      gl_lds16(vp, kb + 8192); gl_lds16(vp + 32 * SB, kb + 8192 + 2048);           \
    }                                                                              \
    const int k0 = (T) * 64;                                                       \
    if (k0 <= wq0 + 31) FLASH_COMPUTE((BUF) * 8192)                                \
  }

  for (int t = 0; t < nt; t += 2) {
    DO_STEP(t, 0)
    DO_STEP(t + 1, 1)
  }

  const float l_full = l_half + __shfl_xor(l_half, 32);
  const float inv_l = 1.f / l_full;
  unsigned short* op = outp + (rowbase + qg) * HB + h * 64;
#pragma unroll
  for (int tq = 0; tq < 4; ++tq) {
    ushort4 st;
    st.x = f2bf(acc0[4 * tq + 0] * inv_l);
    st.y = f2bf(acc0[4 * tq + 1] * inv_l);
    st.z = f2bf(acc0[4 * tq + 2] * inv_l);
    st.w = f2bf(acc0[4 * tq + 3] * inv_l);
    *(ushort4*)(op + 8 * tq + 4 * hi) = st;
    ushort4 su;
    su.x = f2bf(acc1[4 * tq + 0] * inv_l);
    su.y = f2bf(acc1[4 * tq + 1] * inv_l);
    su.z = f2bf(acc1[4 * tq + 2] * inv_l);
    su.w = f2bf(acc1[4 * tq + 3] * inv_l);
    *(ushort4*)(op + 32 + 8 * tq + 4 * hi) = su;
  }
}

extern "C" void kernel_launch(void* const* d_in, const int* in_sizes, int n_in,
                              void* d_out, int out_size, void* d_ws, size_t ws_size,
                              hipStream_t stream) {
  const float* x      = (const float*)d_in[0];   // [4,2048,1024]
  const float* W_attn = (const float*)d_in[1];   // [1024,3072]
  const float* b_attn = (const float*)d_in[2];   // [3072]
  const float* W_proj = (const float*)d_in[3];   // [1024,1024]
  const float* b_proj = (const float*)d_in[4];   // [1024]
  float* out = (float*)d_out;                    // [4,2048,1024] f32

  char* ws = (char*)d_ws;
  unsigned short* x_bf    = (unsigned short*)(ws);                 // 16777216 B
  unsigned short* Wt_attn = (unsigned short*)(ws + 16777216);      //  6291456 B
  unsigned short* Wt_proj = (unsigned short*)(ws + 23068672);      //  2097152 B
  unsigned short* qkv     = (unsigned short*)(ws + 25165824);      // 50331648 B
  unsigned short* attn    = (unsigned short*)(ws + 75497472);      // 16777216 B
  // Fused path: Vt gets its own region (x_bf is LIVE during the qkv GEMM).
  // Fallback: Vt aliases x_bf and uses the transpose_v kernel.
  const bool fuse = ws_size >= (size_t)92274688 + 16777216;
  unsigned short* VtF = (unsigned short*)(ws + 92274688);
  unsigned short* Vt  = fuse ? VtF : x_bf;

  // fused prep: cvt(x) + W_attn^T + W_proj^T in one launch
  prep_all<<<12288, 256, 0, stream>>>(x, x_bf, W_attn, Wt_attn, W_proj, Wt_proj);

  // qkv = x @ W_attn + b_attn (bf16 out) — grid 8x32 = 256 = 1/CU exact
  if (fuse) {
    gemm_v9<true><<<dim3(8, 32), 512, 0, stream>>>(x_bf, Wt_attn, b_attn, qkv, VtF,
                                                   8192, 3072, 1024);
  } else {
    gemm_v9<false><<<dim3(8, 32), 512, 0, stream>>>(x_bf, Wt_attn, b_attn, qkv, nullptr,
                                                    8192, 3072, 1024);
    transpose_v<<<dim3(64, 2, 64), dim3(32, 8), 0, stream>>>(qkv, Vt);
  }
  // flash attention -> attn[8192][1024] (merged heads)
  flash_attn4<<<dim3(64, 16), 256, 0, stream>>>(qkv, Vt, attn);
  // out = attn @ W_proj + b_proj (f32 out) — grid 8x32 = 256 (%8==0)
  gemm_v6<true><<<dim3(8, 32), 512, 0, stream>>>(attn, Wt_proj, b_proj, out,
                                                 8192, 1024, 1024);
}